// Round 2
// baseline (518.829 us; speedup 1.0000x reference)
//
#include <hip/hip_runtime.h>

typedef __bf16 bf16_t;
typedef __bf16 bf16x8 __attribute__((ext_vector_type(8)));
typedef __bf16 bf16x4_v __attribute__((ext_vector_type(4)));
typedef float f32x4 __attribute__((ext_vector_type(4)));

#define AS1 __attribute__((address_space(1)))
#define AS3 __attribute__((address_space(3)))

__device__ __forceinline__ void gload_lds16(const void* g, void* l) {
    __builtin_amdgcn_global_load_lds((AS1 void*)(void*)g, (AS3 void*)l, 16, 0, 0);
}

// ---------------- routing: salpha[m][l][e] = zeta_agg[m][l] * alpha_agg[m][l][e]
__global__ void routing_kernel(
    const float* __restrict__ dom_emb, const float* __restrict__ layer_pos,
    const float* __restrict__ Wi1, const float* __restrict__ bi1,
    const float* __restrict__ Wi2, const float* __restrict__ bi2,
    const float* __restrict__ Wa1, const float* __restrict__ ba1,
    const float* __restrict__ Wa2, const float* __restrict__ ba2,
    const float* __restrict__ gate_logits, const float* __restrict__ R_benefit,
    float* __restrict__ salpha)
{
    constexpr int M = 8, L = 3, E = 4, H = 64;
    __shared__ float zl[M * L];
    __shared__ float al[M * L][E];
    __shared__ float zeta_all[M][L];
    __shared__ float alpha_all[M][L][E];
    const int t = threadIdx.x;
    const int ml = t >> 3, js = t & 7;
    if (ml < M * L) {
        const int m = ml / L, l = ml % L;
        float zacc = 0.f;
        float aacc[E] = {0.f, 0.f, 0.f, 0.f};
        for (int jj = 0; jj < 8; ++jj) {
            const int j = js * 8 + jj;
            float hz = bi1[j], ha = ba1[j];
            for (int i = 0; i < H; ++i) {
                const float de = dom_emb[m * H + i];
                const float lp = layer_pos[l * H + i];
                hz += de * Wi1[j * 2 * H + i] + lp * Wi1[j * 2 * H + H + i];
                ha += de * Wa1[j * 2 * H + i] + lp * Wa1[j * 2 * H + H + i];
            }
            hz = fmaxf(hz, 0.f); ha = fmaxf(ha, 0.f);
            zacc += hz * Wi2[j];
            for (int e = 0; e < E; ++e) aacc[e] += ha * Wa2[e * H + j];
        }
        #pragma unroll
        for (int off = 4; off >= 1; off >>= 1) {
            zacc += __shfl_down(zacc, off, 8);
            for (int e = 0; e < E; ++e) aacc[e] += __shfl_down(aacc[e], off, 8);
        }
        if (js == 0) {
            zl[ml] = zacc + bi2[0];
            for (int e = 0; e < E; ++e) al[ml][e] = aacc[e] + ba2[e];
        }
    }
    __syncthreads();
    if (t < M) {
        const int m = t;
        // zeta: top-2 of L=3 (drop argmin; ties -> later index dropped, matching top_k)
        float v[3] = { zl[m * L + 0], zl[m * L + 1], zl[m * L + 2] };
        int di = 0; float dv = v[0];
        for (int i = 1; i < 3; ++i) if (v[i] <= dv) { dv = v[i]; di = i; }
        float mx = -1e30f;
        for (int i = 0; i < 3; ++i) if (i != di) mx = fmaxf(mx, v[i]);
        float s = 0.f, ev[3];
        for (int i = 0; i < 3; ++i) { ev[i] = (i == di) ? 0.f : expf(v[i] - mx); s += ev[i]; }
        for (int i = 0; i < 3; ++i) zeta_all[m][i] = ev[i] / s;
        // alpha: top-2 of E=4 per layer (ties -> lower index kept, matching top_k)
        for (int l = 0; l < L; ++l) {
            float a[4];
            for (int e = 0; e < 4; ++e) a[e] = al[m * L + l][e];
            int i1 = 0;
            for (int e = 1; e < 4; ++e) if (a[e] > a[i1]) i1 = e;
            int i2 = -1;
            for (int e = 0; e < 4; ++e) { if (e == i1) continue; if (i2 < 0 || a[e] > a[i2]) i2 = e; }
            const float mx2 = fmaxf(a[i1], a[i2]);
            const float e1 = expf(a[i1] - mx2), e2 = expf(a[i2] - mx2);
            const float ss = e1 + e2;
            for (int e = 0; e < 4; ++e) alpha_all[m][l][e] = 0.f;
            alpha_all[m][l][i1] = e1 / ss;
            alpha_all[m][l][i2] = e2 / ss;
        }
    }
    __syncthreads();
    if (t < M) {
        const int m = t;
        float Rrow[8]; float rs = 0.f;
        for (int n = 0; n < M; ++n) {
            const float g = gate_logits[m * M + n];
            const float rr = log1pf(expf(g)) * R_benefit[m * M + n];  // softplus * benefit
            Rrow[n] = rr; rs += rr;
        }
        rs = fmaxf(rs, 1e-12f);
        for (int l = 0; l < L; ++l) {
            float zag = 0.f, aag[4] = {0.f, 0.f, 0.f, 0.f};
            for (int n = 0; n < M; ++n) {
                const float w = Rrow[n] / rs;
                zag += w * zeta_all[n][l];
                for (int e = 0; e < 4; ++e) aag[e] += w * alpha_all[n][l][e];
            }
            for (int e = 0; e < 4; ++e) salpha[(m * L + l) * 4 + e] = zag * aag[e];
        }
    }
}

// ---------------- f32 -> bf16 flat convert (n4 = elements/4)
__global__ void cvt_f32_bf16(const float* __restrict__ in, bf16_t* __restrict__ out, const int n4) {
    const int i = blockIdx.x * 256 + threadIdx.x;
    if (i < n4) {
        const float4 v = ((const float4*)in)[i];
        bf16x4_v o;
        o[0] = (__bf16)v.x; o[1] = (__bf16)v.y; o[2] = (__bf16)v.z; o[3] = (__bf16)v.w;
        ((bf16x4_v*)out)[i] = o;
    }
}

// B [E][Dout][r] f32 -> Bepi [Dout][32] bf16, c = e*8+r
__global__ void bepi_cvt(const float* __restrict__ Bsrc, bf16_t* __restrict__ out, const int Dout) {
    const int idx = blockIdx.x * 256 + threadIdx.x;
    if (idx < Dout * 32) {
        const int o = idx >> 5, c = idx & 31, e = c >> 3, r = c & 7;
        out[idx] = (__bf16)Bsrc[((size_t)e * Dout + o) * 8 + r];
    }
}

// ---------------- TW[b][c] = (sum_k h[b][k]*Acat[c][k]) * salpha[dom[b]][layer][c>>3]
// one wave = 16 rows; block = 4 waves = 64 rows. F32IN also emits bf16 cast of input.
template<bool F32IN>
__global__ void __launch_bounds__(256) tw_kernel(
    const void* __restrict__ hin, bf16_t* __restrict__ xb_out,
    const bf16_t* __restrict__ Acat, const float* __restrict__ salpha,
    const int* __restrict__ dom, const int layer, const int K,
    bf16_t* __restrict__ TWb)
{
    const int t = threadIdx.x, wid = t >> 6, lane = t & 63;
    const int rb = blockIdx.x * 64 + wid * 16;
    const int ln15 = lane & 15, kg = (lane >> 4) * 8;
    const int row = rb + ln15;
    f32x4 acc0 = {0.f, 0.f, 0.f, 0.f}, acc1 = {0.f, 0.f, 0.f, 0.f};
    const bf16_t* pa0 = Acat + (size_t)ln15 * K + kg;
    const bf16_t* pa1 = pa0 + (size_t)16 * K;
    for (int k0 = 0; k0 < K; k0 += 32) {
        bf16x8 a;
        if constexpr (F32IN) {
            const float* px = (const float*)hin + (size_t)row * K + k0 + kg;
            const float4 x0 = *(const float4*)px;
            const float4 x1 = *(const float4*)(px + 4);
            a[0] = (__bf16)x0.x; a[1] = (__bf16)x0.y; a[2] = (__bf16)x0.z; a[3] = (__bf16)x0.w;
            a[4] = (__bf16)x1.x; a[5] = (__bf16)x1.y; a[6] = (__bf16)x1.z; a[7] = (__bf16)x1.w;
            *(bf16x8*)(xb_out + (size_t)row * K + k0 + kg) = a;   // free bf16 cast of x
        } else {
            a = *(const bf16x8*)((const bf16_t*)hin + (size_t)row * K + k0 + kg);
        }
        const bf16x8 b0 = *(const bf16x8*)(pa0 + k0);
        const bf16x8 b1 = *(const bf16x8*)(pa1 + k0);
        acc0 = __builtin_amdgcn_mfma_f32_16x16x32_bf16(a, b0, acc0, 0, 0, 0);
        acc1 = __builtin_amdgcn_mfma_f32_16x16x32_bf16(a, b1, acc1, 0, 0, 0);
    }
    // C/D layout: col = lane&15, row = (lane>>4)*4 + i   [measured m89]
    const int rbase = rb + (lane >> 4) * 4;
    #pragma unroll
    for (int i = 0; i < 4; ++i) {
        const int r2 = rbase + i;
        const int d = dom[r2];
        const float* sa = salpha + (d * 3 + layer) * 4;
        const float s0 = sa[ln15 >> 3];          // c = ln15      -> e in {0,1}
        const float s1 = sa[2 + (ln15 >> 3)];    // c = 16+ln15   -> e in {2,3}
        TWb[(size_t)r2 * 32 + ln15]      = (__bf16)(acc0[i] * s0);
        TWb[(size_t)r2 * 32 + 16 + ln15] = (__bf16)(acc1[i] * s1);
    }
}

// ---------------- main GEMM: out = relu(A @ W^T + bias + TW @ Bepi^T)
// 128x128 tile, 4 waves (2x2, 64x64 each), BK=32, global_load_lds staging,
// LoRA folded in as one extra K-step (TW/Bepi are [rows][32] = one BK tile).
// Staging: tile is BM*BK = 4096 elem = 8KB; one gload_lds16 sweep (256thr x 16B)
// covers 4KB = 64 rows -> TWO sweeps per matrix per K-step (rows 0-63, 64-127).
#define BM 128
#define BN 128
#define BK 32

template<bool OUT_F32>
__global__ void __launch_bounds__(256) gemm_lora(
    const bf16_t* __restrict__ Abuf, const bf16_t* __restrict__ Wbuf,
    const float* __restrict__ bias, const bf16_t* __restrict__ TWb,
    const bf16_t* __restrict__ Bepi, void* __restrict__ outp,
    const int N, const int K)
{
    __shared__ bf16_t lA[BM * BK];
    __shared__ bf16_t lB[BN * BK];
    const int t = threadIdx.x;
    const int row0 = blockIdx.y * BM;
    const int col0 = blockIdx.x * BN;
    const int wid = t >> 6, lane = t & 63;
    const int wr = wid >> 1, wc = wid & 1;
    const int ln15 = lane & 15, kg = (lane >> 4) * 8;
    const int srow = t >> 2, sg8 = (t & 3) * 8;       // staging: thread t -> row t/4, 16B group t%4
    const bf16_t* gA = Abuf + (size_t)(row0 + srow) * K + sg8;
    const bf16_t* gB = Wbuf + (size_t)(col0 + srow) * K + sg8;
    bf16_t* ldA  = &lA[t * 8];                         // sweep 1: rows 0..63
    bf16_t* ldA2 = &lA[2048 + t * 8];                  // sweep 2: rows 64..127
    bf16_t* ldB  = &lB[t * 8];
    bf16_t* ldB2 = &lB[2048 + t * 8];
    f32x4 acc[4][4] = {};
    const int aoff = (wr * 64 + ln15) * BK + kg;
    const int boff = (wc * 64 + ln15) * BK + kg;

    auto compute_tile = [&]() {
        bf16x8 af[4], bfr[4];
        #pragma unroll
        for (int m = 0; m < 4; ++m) af[m] = *(const bf16x8*)&lA[aoff + m * 16 * BK];
        #pragma unroll
        for (int n = 0; n < 4; ++n) bfr[n] = *(const bf16x8*)&lB[boff + n * 16 * BK];
        #pragma unroll
        for (int m = 0; m < 4; ++m)
            #pragma unroll
            for (int n = 0; n < 4; ++n)
                acc[m][n] = __builtin_amdgcn_mfma_f32_16x16x32_bf16(af[m], bfr[n], acc[m][n], 0, 0, 0);
    };

    const size_t half = (size_t)64 * K;                // +64 rows in global
    const int nk = K / BK;
    for (int kt = 0; kt < nk; ++kt) {
        gload_lds16(gA + kt * BK, ldA);
        gload_lds16(gA + half + kt * BK, ldA2);
        gload_lds16(gB + kt * BK, ldB);
        gload_lds16(gB + half + kt * BK, ldB2);
        __syncthreads();
        compute_tile();
        __syncthreads();
    }
    // LoRA K-step: TW [rows][32], Bepi [cols][32] stage exactly like a BK tile
    gload_lds16(TWb + (size_t)(row0 + srow) * 32 + sg8, ldA);
    gload_lds16(TWb + (size_t)(row0 + 64 + srow) * 32 + sg8, ldA2);
    gload_lds16(Bepi + (size_t)(col0 + srow) * 32 + sg8, ldB);
    gload_lds16(Bepi + (size_t)(col0 + 64 + srow) * 32 + sg8, ldB2);
    __syncthreads();
    compute_tile();

    const int orow = row0 + wr * 64 + (lane >> 4) * 4;
    const int ocol = col0 + wc * 64 + ln15;
    #pragma unroll
    for (int n = 0; n < 4; ++n) {
        const int col = ocol + n * 16;
        const float bn = bias[col];
        #pragma unroll
        for (int m = 0; m < 4; ++m) {
            const int rbase = orow + m * 16;
            #pragma unroll
            for (int i = 0; i < 4; ++i) {
                const float v = fmaxf(acc[m][n][i] + bn, 0.f);
                if constexpr (OUT_F32)
                    ((float*)outp)[(size_t)(rbase + i) * N + col] = v;
                else
                    ((bf16_t*)outp)[(size_t)(rbase + i) * N + col] = (__bf16)v;
            }
        }
    }
}

extern "C" void kernel_launch(void* const* d_in, const int* in_sizes, int n_in,
                              void* d_out, int out_size, void* d_ws, size_t ws_size,
                              hipStream_t stream)
{
    const float* x    = (const float*)d_in[0];
    const int*   dom  = (const int*)d_in[1];
    const float* W1   = (const float*)d_in[2];  const float* b1  = (const float*)d_in[3];
    const float* W2   = (const float*)d_in[4];  const float* b2  = (const float*)d_in[5];
    const float* W3   = (const float*)d_in[6];  const float* b3  = (const float*)d_in[7];
    const float* A1   = (const float*)d_in[8];  const float* B1  = (const float*)d_in[9];
    const float* A2   = (const float*)d_in[10]; const float* B2  = (const float*)d_in[11];
    const float* A3   = (const float*)d_in[12]; const float* B3  = (const float*)d_in[13];
    const float* dome = (const float*)d_in[14]; const float* lpos = (const float*)d_in[15];
    const float* Wi1  = (const float*)d_in[16]; const float* bi1 = (const float*)d_in[17];
    const float* Wi2  = (const float*)d_in[18]; const float* bi2 = (const float*)d_in[19];
    const float* Wa1  = (const float*)d_in[20]; const float* ba1 = (const float*)d_in[21];
    const float* Wa2  = (const float*)d_in[22]; const float* ba2 = (const float*)d_in[23];
    const float* gate = (const float*)d_in[24]; const float* Rb  = (const float*)d_in[25];
    (void)in_sizes; (void)n_in; (void)out_size; (void)ws_size;

    constexpr int Bsz = 16384, D0 = 2048, D1 = 2048, D2 = 1024, D3 = 512;

    char* ws = (char*)d_ws;
    size_t off = 0;
    auto alloc = [&](size_t bytes) -> void* {
        void* p = ws + off;
        off = (off + bytes + 255) & ~(size_t)255;
        return p;
    };
    float*  salpha = (float*) alloc(8 * 3 * 4 * sizeof(float));
    bf16_t* W1b = (bf16_t*)alloc((size_t)D1 * D0 * 2);
    bf16_t* W2b = (bf16_t*)alloc((size_t)D2 * D1 * 2);
    bf16_t* W3b = (bf16_t*)alloc((size_t)D3 * D2 * 2);
    bf16_t* Ac1 = (bf16_t*)alloc((size_t)32 * D0 * 2);
    bf16_t* Ac2 = (bf16_t*)alloc((size_t)32 * D1 * 2);
    bf16_t* Ac3 = (bf16_t*)alloc((size_t)32 * D2 * 2);
    bf16_t* Be1 = (bf16_t*)alloc((size_t)D1 * 32 * 2);
    bf16_t* Be2 = (bf16_t*)alloc((size_t)D2 * 32 * 2);
    bf16_t* Be3 = (bf16_t*)alloc((size_t)D3 * 32 * 2);
    bf16_t* TWb = (bf16_t*)alloc((size_t)Bsz * 32 * 2);
    bf16_t* xb  = (bf16_t*)alloc((size_t)Bsz * D0 * 2);
    bf16_t* h1b = (bf16_t*)alloc((size_t)Bsz * D1 * 2);
    bf16_t* h2b = xb;  // xb is dead after layer-1 GEMM; reuse for h2 (33.5MB < 64MB)
    // total ws: ~143 MiB

    routing_kernel<<<1, 256, 0, stream>>>(dome, lpos, Wi1, bi1, Wi2, bi2,
                                          Wa1, ba1, Wa2, ba2, gate, Rb, salpha);

    cvt_f32_bf16<<<(D1 * D0 / 4 + 255) / 256, 256, 0, stream>>>(W1, W1b, D1 * D0 / 4);
    cvt_f32_bf16<<<(D2 * D1 / 4 + 255) / 256, 256, 0, stream>>>(W2, W2b, D2 * D1 / 4);
    cvt_f32_bf16<<<(D3 * D2 / 4 + 255) / 256, 256, 0, stream>>>(W3, W3b, D3 * D2 / 4);
    cvt_f32_bf16<<<(32 * D0 / 4 + 255) / 256, 256, 0, stream>>>(A1, Ac1, 32 * D0 / 4);
    cvt_f32_bf16<<<(32 * D1 / 4 + 255) / 256, 256, 0, stream>>>(A2, Ac2, 32 * D1 / 4);
    cvt_f32_bf16<<<(32 * D2 / 4 + 255) / 256, 256, 0, stream>>>(A3, Ac3, 32 * D2 / 4);
    bepi_cvt<<<(D1 * 32 + 255) / 256, 256, 0, stream>>>(B1, Be1, D1);
    bepi_cvt<<<(D2 * 32 + 255) / 256, 256, 0, stream>>>(B2, Be2, D2);
    bepi_cvt<<<(D3 * 32 + 255) / 256, 256, 0, stream>>>(B3, Be3, D3);

    // layer 1
    tw_kernel<true><<<Bsz / 64, 256, 0, stream>>>(x, xb, Ac1, salpha, dom, 0, D0, TWb);
    gemm_lora<false><<<dim3(D1 / BN, Bsz / BM), 256, 0, stream>>>(xb, W1b, b1, TWb, Be1, h1b, D1, D0);
    // layer 2
    tw_kernel<false><<<Bsz / 64, 256, 0, stream>>>(h1b, nullptr, Ac2, salpha, dom, 1, D1, TWb);
    gemm_lora<false><<<dim3(D2 / BN, Bsz / BM), 256, 0, stream>>>(h1b, W2b, b2, TWb, Be2, h2b, D2, D1);
    // layer 3 (f32 out)
    tw_kernel<false><<<Bsz / 64, 256, 0, stream>>>(h2b, nullptr, Ac3, salpha, dom, 2, D2, TWb);
    gemm_lora<true><<<dim3(D3 / BN, Bsz / BM), 256, 0, stream>>>(h2b, W3b, b3, TWb, Be3, d_out, D3, D2);
}

// Round 3
// 444.546 us; speedup vs baseline: 1.1671x; 1.1671x over previous
//
#include <hip/hip_runtime.h>

typedef __bf16 bf16_t;
typedef __bf16 bf16x8 __attribute__((ext_vector_type(8)));
typedef __bf16 bf16x4_v __attribute__((ext_vector_type(4)));
typedef float f32x4 __attribute__((ext_vector_type(4)));

#define AS1 __attribute__((address_space(1)))
#define AS3 __attribute__((address_space(3)))

__device__ __forceinline__ void gload_lds16(const void* g, void* l) {
    __builtin_amdgcn_global_load_lds((AS1 void*)(void*)g, (AS3 void*)l, 16, 0, 0);
}

// ---------------- routing: salpha[m][l][e] = zeta_agg[m][l] * alpha_agg[m][l][e]
__global__ void routing_kernel(
    const float* __restrict__ dom_emb, const float* __restrict__ layer_pos,
    const float* __restrict__ Wi1, const float* __restrict__ bi1,
    const float* __restrict__ Wi2, const float* __restrict__ bi2,
    const float* __restrict__ Wa1, const float* __restrict__ ba1,
    const float* __restrict__ Wa2, const float* __restrict__ ba2,
    const float* __restrict__ gate_logits, const float* __restrict__ R_benefit,
    float* __restrict__ salpha)
{
    constexpr int M = 8, L = 3, E = 4, H = 64;
    __shared__ float zl[M * L];
    __shared__ float al[M * L][E];
    __shared__ float zeta_all[M][L];
    __shared__ float alpha_all[M][L][E];
    const int t = threadIdx.x;
    const int ml = t >> 3, js = t & 7;
    if (ml < M * L) {
        const int m = ml / L, l = ml % L;
        float zacc = 0.f;
        float aacc[E] = {0.f, 0.f, 0.f, 0.f};
        for (int jj = 0; jj < 8; ++jj) {
            const int j = js * 8 + jj;
            float hz = bi1[j], ha = ba1[j];
            for (int i = 0; i < H; ++i) {
                const float de = dom_emb[m * H + i];
                const float lp = layer_pos[l * H + i];
                hz += de * Wi1[j * 2 * H + i] + lp * Wi1[j * 2 * H + H + i];
                ha += de * Wa1[j * 2 * H + i] + lp * Wa1[j * 2 * H + H + i];
            }
            hz = fmaxf(hz, 0.f); ha = fmaxf(ha, 0.f);
            zacc += hz * Wi2[j];
            for (int e = 0; e < E; ++e) aacc[e] += ha * Wa2[e * H + j];
        }
        #pragma unroll
        for (int off = 4; off >= 1; off >>= 1) {
            zacc += __shfl_down(zacc, off, 8);
            for (int e = 0; e < E; ++e) aacc[e] += __shfl_down(aacc[e], off, 8);
        }
        if (js == 0) {
            zl[ml] = zacc + bi2[0];
            for (int e = 0; e < E; ++e) al[ml][e] = aacc[e] + ba2[e];
        }
    }
    __syncthreads();
    if (t < M) {
        const int m = t;
        float v[3] = { zl[m * L + 0], zl[m * L + 1], zl[m * L + 2] };
        int di = 0; float dv = v[0];
        for (int i = 1; i < 3; ++i) if (v[i] <= dv) { dv = v[i]; di = i; }
        float mx = -1e30f;
        for (int i = 0; i < 3; ++i) if (i != di) mx = fmaxf(mx, v[i]);
        float s = 0.f, ev[3];
        for (int i = 0; i < 3; ++i) { ev[i] = (i == di) ? 0.f : expf(v[i] - mx); s += ev[i]; }
        for (int i = 0; i < 3; ++i) zeta_all[m][i] = ev[i] / s;
        for (int l = 0; l < L; ++l) {
            float a[4];
            for (int e = 0; e < 4; ++e) a[e] = al[m * L + l][e];
            int i1 = 0;
            for (int e = 1; e < 4; ++e) if (a[e] > a[i1]) i1 = e;
            int i2 = -1;
            for (int e = 0; e < 4; ++e) { if (e == i1) continue; if (i2 < 0 || a[e] > a[i2]) i2 = e; }
            const float mx2 = fmaxf(a[i1], a[i2]);
            const float e1 = expf(a[i1] - mx2), e2 = expf(a[i2] - mx2);
            const float ss = e1 + e2;
            for (int e = 0; e < 4; ++e) alpha_all[m][l][e] = 0.f;
            alpha_all[m][l][i1] = e1 / ss;
            alpha_all[m][l][i2] = e2 / ss;
        }
    }
    __syncthreads();
    if (t < M) {
        const int m = t;
        float Rrow[8]; float rs = 0.f;
        for (int n = 0; n < M; ++n) {
            const float g = gate_logits[m * M + n];
            const float rr = log1pf(expf(g)) * R_benefit[m * M + n];
            Rrow[n] = rr; rs += rr;
        }
        rs = fmaxf(rs, 1e-12f);
        for (int l = 0; l < L; ++l) {
            float zag = 0.f, aag[4] = {0.f, 0.f, 0.f, 0.f};
            for (int n = 0; n < M; ++n) {
                const float w = Rrow[n] / rs;
                zag += w * zeta_all[n][l];
                for (int e = 0; e < 4; ++e) aag[e] += w * alpha_all[n][l][e];
            }
            for (int e = 0; e < 4; ++e) salpha[(m * L + l) * 4 + e] = zag * aag[e];
        }
    }
}

// ---------------- f32 -> bf16 flat convert
__global__ void cvt_f32_bf16(const float* __restrict__ in, bf16_t* __restrict__ out, const int n4) {
    const int i = blockIdx.x * 256 + threadIdx.x;
    if (i < n4) {
        const float4 v = ((const float4*)in)[i];
        bf16x4_v o;
        o[0] = (__bf16)v.x; o[1] = (__bf16)v.y; o[2] = (__bf16)v.z; o[3] = (__bf16)v.w;
        ((bf16x4_v*)out)[i] = o;
    }
}

// B [E][Dout][r] f32 -> Bepi [Dout][32] bf16, c = e*8+r
__global__ void bepi_cvt(const float* __restrict__ Bsrc, bf16_t* __restrict__ out, const int Dout) {
    const int idx = blockIdx.x * 256 + threadIdx.x;
    if (idx < Dout * 32) {
        const int o = idx >> 5, c = idx & 31, e = c >> 3, r = c & 7;
        out[idx] = (__bf16)Bsrc[((size_t)e * Dout + o) * 8 + r];
    }
}

// ---------------- TW[b][c] = (sum_k h[b][k]*Acat[c][k]) * salpha[dom[b]][layer][c>>3]
template<bool F32IN>
__global__ void __launch_bounds__(256) tw_kernel(
    const void* __restrict__ hin, bf16_t* __restrict__ xb_out,
    const bf16_t* __restrict__ Acat, const float* __restrict__ salpha,
    const int* __restrict__ dom, const int layer, const int K,
    bf16_t* __restrict__ TWb)
{
    const int t = threadIdx.x, wid = t >> 6, lane = t & 63;
    const int rb = blockIdx.x * 64 + wid * 16;
    const int ln15 = lane & 15, kg = (lane >> 4) * 8;
    const int row = rb + ln15;
    f32x4 acc0 = {0.f, 0.f, 0.f, 0.f}, acc1 = {0.f, 0.f, 0.f, 0.f};
    const bf16_t* pa0 = Acat + (size_t)ln15 * K + kg;
    const bf16_t* pa1 = pa0 + (size_t)16 * K;
    for (int k0 = 0; k0 < K; k0 += 32) {
        bf16x8 a;
        if constexpr (F32IN) {
            const float* px = (const float*)hin + (size_t)row * K + k0 + kg;
            const float4 x0 = *(const float4*)px;
            const float4 x1 = *(const float4*)(px + 4);
            a[0] = (__bf16)x0.x; a[1] = (__bf16)x0.y; a[2] = (__bf16)x0.z; a[3] = (__bf16)x0.w;
            a[4] = (__bf16)x1.x; a[5] = (__bf16)x1.y; a[6] = (__bf16)x1.z; a[7] = (__bf16)x1.w;
            *(bf16x8*)(xb_out + (size_t)row * K + k0 + kg) = a;
        } else {
            a = *(const bf16x8*)((const bf16_t*)hin + (size_t)row * K + k0 + kg);
        }
        const bf16x8 b0 = *(const bf16x8*)(pa0 + k0);
        const bf16x8 b1 = *(const bf16x8*)(pa1 + k0);
        acc0 = __builtin_amdgcn_mfma_f32_16x16x32_bf16(a, b0, acc0, 0, 0, 0);
        acc1 = __builtin_amdgcn_mfma_f32_16x16x32_bf16(a, b1, acc1, 0, 0, 0);
    }
    const int rbase = rb + (lane >> 4) * 4;
    #pragma unroll
    for (int i = 0; i < 4; ++i) {
        const int r2 = rbase + i;
        const int d = dom[r2];
        const float* sa = salpha + (d * 3 + layer) * 4;
        const float s0 = sa[ln15 >> 3];
        const float s1 = sa[2 + (ln15 >> 3)];
        TWb[(size_t)r2 * 32 + ln15]      = (__bf16)(acc0[i] * s0);
        TWb[(size_t)r2 * 32 + 16 + ln15] = (__bf16)(acc1[i] * s1);
    }
}

// ================= 256x256 8-phase GEMM + fused LoRA K-step =================
// BM=BN=256, BK=64 (2 K-halves of 32), 512 threads = 8 waves (2M x 4N).
// LDS 128 KiB: A/B x 2 dbuf x 2 k-half chunks (16 KB each, [256 rows][32k]).
// Chunk swizzle: 16B slot sigma = s ^ (row&3) ^ ((row>>2)&1)  (bank-even).
// Stage = linear LDS dest + inverse-swizzled global source (2 gloads/chunk).
// Phase order per K-tile T (p=T&1): P1 (M0,k0) reads A4+B4, stages T+1.Ak1;
// P2 (M1,k0) reads A4, stages T+2.Bk0; P3 (M1,k1) reads A4+B4, stages T+2.Ak0;
// P4 (M0,k1) reads A4, stages T+2.Bk1, vmcnt(6).
// Race-check: overwrite targets read-complete at stage-issue barrier;
// vmcnt(6) at P4 guarantees loads through previous P1 (= all of tile T+1).

__device__ __forceinline__ void stage_chunk(const bf16_t* g, int ldK, char* chunk, int t) {
    #pragma unroll
    for (int w = 0; w < 2; ++w) {
        const int rt = w * 512 + t;
        const int row = rt >> 2;
        const int s = (rt & 3) ^ (row & 3) ^ ((row >> 2) & 1);
        gload_lds16(g + (size_t)row * ldK + s * 8, chunk + w * 8192 + t * 16);
    }
}

__global__ void __launch_bounds__(512, 2) gemm_lora8(
    const bf16_t* __restrict__ Abuf, const bf16_t* __restrict__ Wbuf,
    const float* __restrict__ bias, const bf16_t* __restrict__ TWb,
    const bf16_t* __restrict__ Bepi, bf16_t* __restrict__ outp,
    const int N, const int K, const int nwg_n)
{
    __shared__ __align__(1024) char lds[131072];
    const int t = threadIdx.x;
    const int wid = t >> 6, lane = t & 63;
    const int wm = wid >> 2, wn = wid & 3;
    // T1: bijective XCD swizzle (grid % 8 == 0)
    const int cpx = gridDim.x >> 3;
    const int wg = (blockIdx.x & 7) * cpx + (blockIdx.x >> 3);
    const int row0 = (wg / nwg_n) * 256, col0 = (wg % nwg_n) * 256;

    const int r15 = lane & 15;
    const int swb = ((lane >> 4) ^ (r15 & 3) ^ ((r15 >> 2) & 1)) << 4;  // slot byte offset
    const int arow = wm * 128 + r15;   // + h*64 + mf*16 (multiples of 16: swizzle bits safe)
    const int brow = wn * 64 + r15;    // + nf*16

    auto achunk = [&](int p, int kh) -> char* { return lds + (((p << 1) + kh) << 14); };
    auto bchunk = [&](int p, int kh) -> char* { return lds + 65536 + (((p << 1) + kh) << 14); };

    const bf16_t* Ab = Abuf + (size_t)row0 * K;
    const bf16_t* Bb = Wbuf + (size_t)col0 * K;

    f32x4 acc[8][4] = {};
    bf16x8 aF[4], bF[4];

    auto readA = [&](char* c, int h) {
        #pragma unroll
        for (int mf = 0; mf < 4; ++mf)
            aF[mf] = *(const bf16x8*)(c + ((arow + h * 64 + mf * 16) << 6) + swb);
    };
    auto readB = [&](char* c) {
        #pragma unroll
        for (int nf = 0; nf < 4; ++nf)
            bF[nf] = *(const bf16x8*)(c + ((brow + nf * 16) << 6) + swb);
    };
    auto mfma16 = [&](int h) {
        __builtin_amdgcn_s_setprio(1);
        #pragma unroll
        for (int mf = 0; mf < 4; ++mf)
            #pragma unroll
            for (int nf = 0; nf < 4; ++nf)
                acc[h * 4 + mf][nf] =
                    __builtin_amdgcn_mfma_f32_16x16x32_bf16(aF[mf], bF[nf], acc[h * 4 + mf][nf], 0, 0, 0);
        __builtin_amdgcn_s_setprio(0);
    };
    #define MIDSYNC() do { __builtin_amdgcn_s_barrier(); \
        asm volatile("s_waitcnt lgkmcnt(0)" ::: "memory"); \
        __builtin_amdgcn_sched_barrier(0); } while (0)
    #define ENDBAR() __builtin_amdgcn_s_barrier()

    const int NT = K >> 6;  // K-tiles of 64 (NT >= 2)

    // Prologue: tile0 {Bk0,Ak0,Bk1,Ak1}, tile1 {Bk0,Ak0,Bk1}; vmcnt(6) => tile0 done.
    stage_chunk(Bb,      K, bchunk(0, 0), t);
    stage_chunk(Ab,      K, achunk(0, 0), t);
    stage_chunk(Bb + 32, K, bchunk(0, 1), t);
    stage_chunk(Ab + 32, K, achunk(0, 1), t);
    stage_chunk(Bb + 64, K, bchunk(1, 0), t);
    stage_chunk(Ab + 64, K, achunk(1, 0), t);
    stage_chunk(Bb + 96, K, bchunk(1, 1), t);
    asm volatile("s_waitcnt vmcnt(6)" ::: "memory");
    __builtin_amdgcn_s_barrier();

    for (int T = 0; T < NT; ++T) {
        const int p = T & 1, q = p ^ 1;
        const int ko1 = (T + 1) << 6, ko2 = (T + 2) << 6;
        // P1: (M0,k0)
        if (T + 1 < NT) stage_chunk(Ab + ko1 + 32, K, achunk(q, 1), t);
        readA(achunk(p, 0), 0);
        readB(bchunk(p, 0));
        if (T == NT - 1) asm volatile("s_waitcnt vmcnt(0)" ::: "memory");  // tail drain
        MIDSYNC();
        mfma16(0);
        ENDBAR();
        // P2: (M1,k0)
        if (T + 2 < NT) stage_chunk(Bb + ko2, K, bchunk(p, 0), t);
        readA(achunk(p, 0), 1);
        MIDSYNC();
        mfma16(1);
        ENDBAR();
        // P3: (M1,k1)
        if (T + 2 < NT) stage_chunk(Ab + ko2, K, achunk(p, 0), t);
        readA(achunk(p, 1), 1);
        readB(bchunk(p, 1));
        MIDSYNC();
        mfma16(1);
        ENDBAR();
        // P4: (M0,k1)
        if (T + 2 < NT) stage_chunk(Bb + ko2 + 32, K, bchunk(p, 1), t);
        readA(achunk(p, 1), 0);
        asm volatile("s_waitcnt vmcnt(6)" ::: "memory");
        MIDSYNC();
        mfma16(0);
        ENDBAR();
    }

    // LoRA tail: one 32-wide K-step from TW [rows][32] / Bepi [cols][32].
    {
        const int q2 = NT & 1;
        stage_chunk(TWb + (size_t)row0 * 32, 32, achunk(q2, 0), t);
        stage_chunk(Bepi + (size_t)col0 * 32, 32, bchunk(q2, 0), t);
        asm volatile("s_waitcnt vmcnt(0)" ::: "memory");
        __builtin_amdgcn_s_barrier();
        readA(achunk(q2, 0), 0);
        readB(bchunk(q2, 0));
        asm volatile("s_waitcnt lgkmcnt(0)" ::: "memory");
        __builtin_amdgcn_sched_barrier(0);
        mfma16(0);
        readA(achunk(q2, 0), 1);
        asm volatile("s_waitcnt lgkmcnt(0)" ::: "memory");
        __builtin_amdgcn_sched_barrier(0);
        mfma16(1);
    }

    // Epilogue: bias + relu, bf16 store
    const int orow = row0 + wm * 128 + (lane >> 4) * 4;
    const int ocol = col0 + wn * 64 + r15;
    #pragma unroll
    for (int nf = 0; nf < 4; ++nf) {
        const int col = ocol + nf * 16;
        const float bn = bias[col];
        #pragma unroll
        for (int mf = 0; mf < 8; ++mf) {
            const int rbase = orow + mf * 16;
            #pragma unroll
            for (int i = 0; i < 4; ++i) {
                const float v = fmaxf(acc[mf][nf][i] + bn, 0.f);
                outp[(size_t)(rbase + i) * N + col] = (__bf16)v;
            }
        }
    }
    #undef MIDSYNC
    #undef ENDBAR
}

// ---------------- old 128x128 GEMM (kept for layer 3: N=512 grid too small for 256^2)
#define BM 128
#define BN 128
#define BK 32

template<bool OUT_F32>
__global__ void __launch_bounds__(256) gemm_lora(
    const bf16_t* __restrict__ Abuf, const bf16_t* __restrict__ Wbuf,
    const float* __restrict__ bias, const bf16_t* __restrict__ TWb,
    const bf16_t* __restrict__ Bepi, void* __restrict__ outp,
    const int N, const int K)
{
    __shared__ bf16_t lA[BM * BK];
    __shared__ bf16_t lB[BN * BK];
    const int t = threadIdx.x;
    const int row0 = blockIdx.y * BM;
    const int col0 = blockIdx.x * BN;
    const int wid = t >> 6, lane = t & 63;
    const int wr = wid >> 1, wc = wid & 1;
    const int ln15 = lane & 15, kg = (lane >> 4) * 8;
    const int srow = t >> 2, sg8 = (t & 3) * 8;
    const bf16_t* gA = Abuf + (size_t)(row0 + srow) * K + sg8;
    const bf16_t* gB = Wbuf + (size_t)(col0 + srow) * K + sg8;
    bf16_t* ldA  = &lA[t * 8];
    bf16_t* ldA2 = &lA[2048 + t * 8];
    bf16_t* ldB  = &lB[t * 8];
    bf16_t* ldB2 = &lB[2048 + t * 8];
    f32x4 acc[4][4] = {};
    const int aoff = (wr * 64 + ln15) * BK + kg;
    const int boff = (wc * 64 + ln15) * BK + kg;

    auto compute_tile = [&]() {
        bf16x8 af[4], bfr[4];
        #pragma unroll
        for (int m = 0; m < 4; ++m) af[m] = *(const bf16x8*)&lA[aoff + m * 16 * BK];
        #pragma unroll
        for (int n = 0; n < 4; ++n) bfr[n] = *(const bf16x8*)&lB[boff + n * 16 * BK];
        #pragma unroll
        for (int m = 0; m < 4; ++m)
            #pragma unroll
            for (int n = 0; n < 4; ++n)
                acc[m][n] = __builtin_amdgcn_mfma_f32_16x16x32_bf16(af[m], bfr[n], acc[m][n], 0, 0, 0);
    };

    const size_t half = (size_t)64 * K;
    const int nk = K / BK;
    for (int kt = 0; kt < nk; ++kt) {
        gload_lds16(gA + kt * BK, ldA);
        gload_lds16(gA + half + kt * BK, ldA2);
        gload_lds16(gB + kt * BK, ldB);
        gload_lds16(gB + half + kt * BK, ldB2);
        __syncthreads();
        compute_tile();
        __syncthreads();
    }
    gload_lds16(TWb + (size_t)(row0 + srow) * 32 + sg8, ldA);
    gload_lds16(TWb + (size_t)(row0 + 64 + srow) * 32 + sg8, ldA2);
    gload_lds16(Bepi + (size_t)(col0 + srow) * 32 + sg8, ldB);
    gload_lds16(Bepi + (size_t)(col0 + 64 + srow) * 32 + sg8, ldB2);
    __syncthreads();
    compute_tile();

    const int orow = row0 + wr * 64 + (lane >> 4) * 4;
    const int ocol = col0 + wc * 64 + ln15;
    #pragma unroll
    for (int n = 0; n < 4; ++n) {
        const int col = ocol + n * 16;
        const float bn = bias[col];
        #pragma unroll
        for (int m = 0; m < 4; ++m) {
            const int rbase = orow + m * 16;
            #pragma unroll
            for (int i = 0; i < 4; ++i) {
                const float v = fmaxf(acc[m][n][i] + bn, 0.f);
                if constexpr (OUT_F32)
                    ((float*)outp)[(size_t)(rbase + i) * N + col] = v;
                else
                    ((bf16_t*)outp)[(size_t)(rbase + i) * N + col] = (__bf16)v;
            }
        }
    }
}

extern "C" void kernel_launch(void* const* d_in, const int* in_sizes, int n_in,
                              void* d_out, int out_size, void* d_ws, size_t ws_size,
                              hipStream_t stream)
{
    const float* x    = (const float*)d_in[0];
    const int*   dom  = (const int*)d_in[1];
    const float* W1   = (const float*)d_in[2];  const float* b1  = (const float*)d_in[3];
    const float* W2   = (const float*)d_in[4];  const float* b2  = (const float*)d_in[5];
    const float* W3   = (const float*)d_in[6];  const float* b3  = (const float*)d_in[7];
    const float* A1   = (const float*)d_in[8];  const float* B1  = (const float*)d_in[9];
    const float* A2   = (const float*)d_in[10]; const float* B2  = (const float*)d_in[11];
    const float* A3   = (const float*)d_in[12]; const float* B3  = (const float*)d_in[13];
    const float* dome = (const float*)d_in[14]; const float* lpos = (const float*)d_in[15];
    const float* Wi1  = (const float*)d_in[16]; const float* bi1 = (const float*)d_in[17];
    const float* Wi2  = (const float*)d_in[18]; const float* bi2 = (const float*)d_in[19];
    const float* Wa1  = (const float*)d_in[20]; const float* ba1 = (const float*)d_in[21];
    const float* Wa2  = (const float*)d_in[22]; const float* ba2 = (const float*)d_in[23];
    const float* gate = (const float*)d_in[24]; const float* Rb  = (const float*)d_in[25];
    (void)in_sizes; (void)n_in; (void)out_size; (void)ws_size;

    constexpr int Bsz = 16384, D0 = 2048, D1 = 2048, D2 = 1024, D3 = 512;

    char* ws = (char*)d_ws;
    size_t off = 0;
    auto alloc = [&](size_t bytes) -> void* {
        void* p = ws + off;
        off = (off + bytes + 255) & ~(size_t)255;
        return p;
    };
    float*  salpha = (float*) alloc(8 * 3 * 4 * sizeof(float));
    bf16_t* W1b = (bf16_t*)alloc((size_t)D1 * D0 * 2);
    bf16_t* W2b = (bf16_t*)alloc((size_t)D2 * D1 * 2);
    bf16_t* W3b = (bf16_t*)alloc((size_t)D3 * D2 * 2);
    bf16_t* Ac1 = (bf16_t*)alloc((size_t)32 * D0 * 2);
    bf16_t* Ac2 = (bf16_t*)alloc((size_t)32 * D1 * 2);
    bf16_t* Ac3 = (bf16_t*)alloc((size_t)32 * D2 * 2);
    bf16_t* Be1 = (bf16_t*)alloc((size_t)D1 * 32 * 2);
    bf16_t* Be2 = (bf16_t*)alloc((size_t)D2 * 32 * 2);
    bf16_t* Be3 = (bf16_t*)alloc((size_t)D3 * 32 * 2);
    bf16_t* TWb = (bf16_t*)alloc((size_t)Bsz * 32 * 2);
    bf16_t* xb  = (bf16_t*)alloc((size_t)Bsz * D0 * 2);
    bf16_t* h1b = (bf16_t*)alloc((size_t)Bsz * D1 * 2);
    bf16_t* h2b = xb;  // xb dead after layer-1 GEMM

    routing_kernel<<<1, 256, 0, stream>>>(dome, lpos, Wi1, bi1, Wi2, bi2,
                                          Wa1, ba1, Wa2, ba2, gate, Rb, salpha);

    cvt_f32_bf16<<<(D1 * D0 / 4 + 255) / 256, 256, 0, stream>>>(W1, W1b, D1 * D0 / 4);
    cvt_f32_bf16<<<(D2 * D1 / 4 + 255) / 256, 256, 0, stream>>>(W2, W2b, D2 * D1 / 4);
    cvt_f32_bf16<<<(D3 * D2 / 4 + 255) / 256, 256, 0, stream>>>(W3, W3b, D3 * D2 / 4);
    cvt_f32_bf16<<<(32 * D0 / 4 + 255) / 256, 256, 0, stream>>>(A1, Ac1, 32 * D0 / 4);
    cvt_f32_bf16<<<(32 * D1 / 4 + 255) / 256, 256, 0, stream>>>(A2, Ac2, 32 * D1 / 4);
    cvt_f32_bf16<<<(32 * D2 / 4 + 255) / 256, 256, 0, stream>>>(A3, Ac3, 32 * D2 / 4);
    bepi_cvt<<<(D1 * 32 + 255) / 256, 256, 0, stream>>>(B1, Be1, D1);
    bepi_cvt<<<(D2 * 32 + 255) / 256, 256, 0, stream>>>(B2, Be2, D2);
    bepi_cvt<<<(D3 * 32 + 255) / 256, 256, 0, stream>>>(B3, Be3, D3);

    // layer 1: 256^2 8-phase (grid 64x8 = 512 blocks)
    tw_kernel<true><<<Bsz / 64, 256, 0, stream>>>(x, xb, Ac1, salpha, dom, 0, D0, TWb);
    gemm_lora8<<<(Bsz / 256) * (D1 / 256), 512, 0, stream>>>(xb, W1b, b1, TWb, Be1, h1b, D1, D0, D1 / 256);
    // layer 2: 256^2 8-phase (grid 64x4 = 256 blocks)
    tw_kernel<false><<<Bsz / 64, 256, 0, stream>>>(h1b, nullptr, Ac2, salpha, dom, 1, D1, TWb);
    gemm_lora8<<<(Bsz / 256) * (D2 / 256), 512, 0, stream>>>(h1b, W2b, b2, TWb, Be2, h2b, D2, D1, D2 / 256);
    // layer 3 (f32 out, old 128^2 kernel: grid 4x128)
    tw_kernel<false><<<Bsz / 64, 256, 0, stream>>>(h2b, nullptr, Ac3, salpha, dom, 2, D2, TWb);
    gemm_lora<true><<<dim3(D3 / BN, Bsz / BM), 256, 0, stream>>>(h2b, W3b, b3, TWb, Be3, d_out, D3, D2);
}

// Round 4
// 434.318 us; speedup vs baseline: 1.1946x; 1.0235x over previous
//
#include <hip/hip_runtime.h>

typedef __bf16 bf16_t;
typedef __bf16 bf16x8 __attribute__((ext_vector_type(8)));
typedef __bf16 bf16x4_v __attribute__((ext_vector_type(4)));
typedef float f32x4 __attribute__((ext_vector_type(4)));

#define AS1 __attribute__((address_space(1)))
#define AS3 __attribute__((address_space(3)))

__device__ __forceinline__ void gload_lds16(const void* g, void* l) {
    __builtin_amdgcn_global_load_lds((AS1 void*)(void*)g, (AS3 void*)l, 16, 0, 0);
}

// ---------------- routing: salpha[m][l][e] = zeta_agg[m][l] * alpha_agg[m][l][e]
__global__ void routing_kernel(
    const float* __restrict__ dom_emb, const float* __restrict__ layer_pos,
    const float* __restrict__ Wi1, const float* __restrict__ bi1,
    const float* __restrict__ Wi2, const float* __restrict__ bi2,
    const float* __restrict__ Wa1, const float* __restrict__ ba1,
    const float* __restrict__ Wa2, const float* __restrict__ ba2,
    const float* __restrict__ gate_logits, const float* __restrict__ R_benefit,
    float* __restrict__ salpha)
{
    constexpr int M = 8, L = 3, E = 4, H = 64;
    __shared__ float zl[M * L];
    __shared__ float al[M * L][E];
    __shared__ float zeta_all[M][L];
    __shared__ float alpha_all[M][L][E];
    const int t = threadIdx.x;
    const int ml = t >> 3, js = t & 7;
    if (ml < M * L) {
        const int m = ml / L, l = ml % L;
        float zacc = 0.f;
        float aacc[E] = {0.f, 0.f, 0.f, 0.f};
        for (int jj = 0; jj < 8; ++jj) {
            const int j = js * 8 + jj;
            float hz = bi1[j], ha = ba1[j];
            for (int i = 0; i < H; ++i) {
                const float de = dom_emb[m * H + i];
                const float lp = layer_pos[l * H + i];
                hz += de * Wi1[j * 2 * H + i] + lp * Wi1[j * 2 * H + H + i];
                ha += de * Wa1[j * 2 * H + i] + lp * Wa1[j * 2 * H + H + i];
            }
            hz = fmaxf(hz, 0.f); ha = fmaxf(ha, 0.f);
            zacc += hz * Wi2[j];
            for (int e = 0; e < E; ++e) aacc[e] += ha * Wa2[e * H + j];
        }
        #pragma unroll
        for (int off = 4; off >= 1; off >>= 1) {
            zacc += __shfl_down(zacc, off, 8);
            for (int e = 0; e < E; ++e) aacc[e] += __shfl_down(aacc[e], off, 8);
        }
        if (js == 0) {
            zl[ml] = zacc + bi2[0];
            for (int e = 0; e < E; ++e) al[ml][e] = aacc[e] + ba2[e];
        }
    }
    __syncthreads();
    if (t < M) {
        const int m = t;
        float v[3] = { zl[m * L + 0], zl[m * L + 1], zl[m * L + 2] };
        int di = 0; float dv = v[0];
        for (int i = 1; i < 3; ++i) if (v[i] <= dv) { dv = v[i]; di = i; }
        float mx = -1e30f;
        for (int i = 0; i < 3; ++i) if (i != di) mx = fmaxf(mx, v[i]);
        float s = 0.f, ev[3];
        for (int i = 0; i < 3; ++i) { ev[i] = (i == di) ? 0.f : expf(v[i] - mx); s += ev[i]; }
        for (int i = 0; i < 3; ++i) zeta_all[m][i] = ev[i] / s;
        for (int l = 0; l < L; ++l) {
            float a[4];
            for (int e = 0; e < 4; ++e) a[e] = al[m * L + l][e];
            int i1 = 0;
            for (int e = 1; e < 4; ++e) if (a[e] > a[i1]) i1 = e;
            int i2 = -1;
            for (int e = 0; e < 4; ++e) { if (e == i1) continue; if (i2 < 0 || a[e] > a[i2]) i2 = e; }
            const float mx2 = fmaxf(a[i1], a[i2]);
            const float e1 = expf(a[i1] - mx2), e2 = expf(a[i2] - mx2);
            const float ss = e1 + e2;
            for (int e = 0; e < 4; ++e) alpha_all[m][l][e] = 0.f;
            alpha_all[m][l][i1] = e1 / ss;
            alpha_all[m][l][i2] = e2 / ss;
        }
    }
    __syncthreads();
    if (t < M) {
        const int m = t;
        float Rrow[8]; float rs = 0.f;
        for (int n = 0; n < M; ++n) {
            const float g = gate_logits[m * M + n];
            const float rr = log1pf(expf(g)) * R_benefit[m * M + n];
            Rrow[n] = rr; rs += rr;
        }
        rs = fmaxf(rs, 1e-12f);
        for (int l = 0; l < L; ++l) {
            float zag = 0.f, aag[4] = {0.f, 0.f, 0.f, 0.f};
            for (int n = 0; n < M; ++n) {
                const float w = Rrow[n] / rs;
                zag += w * zeta_all[n][l];
                for (int e = 0; e < 4; ++e) aag[e] += w * alpha_all[n][l][e];
            }
            for (int e = 0; e < 4; ++e) salpha[(m * L + l) * 4 + e] = zag * aag[e];
        }
    }
}

// ---------------- f32 -> bf16 flat convert
__global__ void cvt_f32_bf16(const float* __restrict__ in, bf16_t* __restrict__ out, const int n4) {
    const int i = blockIdx.x * 256 + threadIdx.x;
    if (i < n4) {
        const float4 v = ((const float4*)in)[i];
        bf16x4_v o;
        o[0] = (__bf16)v.x; o[1] = (__bf16)v.y; o[2] = (__bf16)v.z; o[3] = (__bf16)v.w;
        ((bf16x4_v*)out)[i] = o;
    }
}

// B [E][Dout][r] f32 -> Bepi [Dout][32] bf16, c = e*8+r
__global__ void bepi_cvt(const float* __restrict__ Bsrc, bf16_t* __restrict__ out, const int Dout) {
    const int idx = blockIdx.x * 256 + threadIdx.x;
    if (idx < Dout * 32) {
        const int o = idx >> 5, c = idx & 31, e = c >> 3, r = c & 7;
        out[idx] = (__bf16)Bsrc[((size_t)e * Dout + o) * 8 + r];
    }
}

// ---------------- TW[b][c] = (sum_k h[b][k]*Acat[c][k]) * salpha[dom[b]][layer][c>>3]
template<bool F32IN>
__global__ void __launch_bounds__(256) tw_kernel(
    const void* __restrict__ hin, bf16_t* __restrict__ xb_out,
    const bf16_t* __restrict__ Acat, const float* __restrict__ salpha,
    const int* __restrict__ dom, const int layer, const int K,
    bf16_t* __restrict__ TWb)
{
    const int t = threadIdx.x, wid = t >> 6, lane = t & 63;
    const int rb = blockIdx.x * 64 + wid * 16;
    const int ln15 = lane & 15, kg = (lane >> 4) * 8;
    const int row = rb + ln15;
    f32x4 acc0 = {0.f, 0.f, 0.f, 0.f}, acc1 = {0.f, 0.f, 0.f, 0.f};
    const bf16_t* pa0 = Acat + (size_t)ln15 * K + kg;
    const bf16_t* pa1 = pa0 + (size_t)16 * K;
    for (int k0 = 0; k0 < K; k0 += 32) {
        bf16x8 a;
        if constexpr (F32IN) {
            const float* px = (const float*)hin + (size_t)row * K + k0 + kg;
            const float4 x0 = *(const float4*)px;
            const float4 x1 = *(const float4*)(px + 4);
            a[0] = (__bf16)x0.x; a[1] = (__bf16)x0.y; a[2] = (__bf16)x0.z; a[3] = (__bf16)x0.w;
            a[4] = (__bf16)x1.x; a[5] = (__bf16)x1.y; a[6] = (__bf16)x1.z; a[7] = (__bf16)x1.w;
            *(bf16x8*)(xb_out + (size_t)row * K + k0 + kg) = a;
        } else {
            a = *(const bf16x8*)((const bf16_t*)hin + (size_t)row * K + k0 + kg);
        }
        const bf16x8 b0 = *(const bf16x8*)(pa0 + k0);
        const bf16x8 b1 = *(const bf16x8*)(pa1 + k0);
        acc0 = __builtin_amdgcn_mfma_f32_16x16x32_bf16(a, b0, acc0, 0, 0, 0);
        acc1 = __builtin_amdgcn_mfma_f32_16x16x32_bf16(a, b1, acc1, 0, 0, 0);
    }
    const int rbase = rb + (lane >> 4) * 4;
    #pragma unroll
    for (int i = 0; i < 4; ++i) {
        const int r2 = rbase + i;
        const int d = dom[r2];
        const float* sa = salpha + (d * 3 + layer) * 4;
        const float s0 = sa[ln15 >> 3];
        const float s1 = sa[2 + (ln15 >> 3)];
        TWb[(size_t)r2 * 32 + ln15]      = (__bf16)(acc0[i] * s0);
        TWb[(size_t)r2 * 32 + 16 + ln15] = (__bf16)(acc1[i] * s1);
    }
}

// ================= 256x256 8-phase GEMM + fused LoRA K-step (m201 geometry) =====
// Chunks = [128 rows][64 k] bf16 = 128B rows, 16KB. A0/A1 = M-halves, B0/B1 = N-halves.
// Swizzle (m201 st_16x32): byte bit5 ^= row bit2 -> read slot' = kq*4 + (s ^ 2*rowbit2);
// staged via inverse-permuted global source, linear LDS dest (involution).
// Staging: P1->T+1.A0, P2->T+1.A1, P4->T+2.B0+B1; vmcnt(4) at P4 == tile T+1 landed.
// A-chunks read in all 4 phases (1-tile-ahead staging only: ~3 phases in flight > HBM lat).

__device__ __forceinline__ void stage_chunk64(const bf16_t* g, int ldK, char* chunk, int t) {
    #pragma unroll
    for (int w = 0; w < 2; ++w) {
        const int d = w * 512 + t;
        const int row = d >> 3;
        const int sl = d & 7;
        const int src = sl ^ (((row >> 2) & 1) << 1);   // inverse swizzle on source
        gload_lds16(g + (size_t)row * ldK + src * 8, chunk + d * 16);
    }
}

// LoRA chunk: [128 rows][32 k] = 64B rows, 8KB, one sweep.
__device__ __forceinline__ void stage_chunk32(const bf16_t* g, char* chunk, int t) {
    const int row = t >> 2;
    const int sl = t & 3;
    const int src = sl ^ (((row >> 2) & 1) << 1);
    gload_lds16(g + (size_t)row * 32 + src * 8, chunk + t * 16);
}

__global__ void __launch_bounds__(512, 2) gemm_lora8(
    const bf16_t* __restrict__ Abuf, const bf16_t* __restrict__ Wbuf,
    const float* __restrict__ bias, const bf16_t* __restrict__ TWb,
    const bf16_t* __restrict__ Bepi, bf16_t* __restrict__ outp,
    const int N, const int K, const int nwg_n)
{
    __shared__ __align__(1024) char lds[131072];
    const int t = threadIdx.x;
    const int wid = t >> 6, lane = t & 63;
    const int wm = wid >> 2, wn = wid & 3, wnh = wn >> 1;
    // T1: bijective XCD swizzle (grid % 8 == 0)
    const int cpx = gridDim.x >> 3;
    const int wg = (blockIdx.x & 7) * cpx + (blockIdx.x >> 3);
    const int row0 = (wg / nwg_n) * 256, col0 = (wg % nwg_n) * 256;

    const int r15 = lane & 15;
    const int swb = ((lane >> 4) ^ (((lane >> 2) & 1) << 1)) << 4;  // (s ^ 2*rowbit2)*16

    auto achunk = [&](int p, int c) -> char* { return lds + (((p << 1) + c) << 14); };
    auto bchunk = [&](int p, int c) -> char* { return lds + 65536 + (((p << 1) + c) << 14); };

    const bf16_t* Ab = Abuf + (size_t)row0 * K;
    const bf16_t* Bb = Wbuf + (size_t)col0 * K;
    const size_t halfA = (size_t)128 * K;

    f32x4 acc[8][4] = {};
    bf16x8 aF[4], bF[4];

    auto readA = [&](char* c, int mbase, int kq) {
        #pragma unroll
        for (int i = 0; i < 4; ++i)
            aF[i] = *(const bf16x8*)(c + (((mbase + i) * 16 + r15) << 7) + (kq << 6) + swb);
    };
    auto readB = [&](char* c, int kq) {
        #pragma unroll
        for (int nf = 0; nf < 4; ++nf)
            bF[nf] = *(const bf16x8*)(c + ((((wn & 1) * 64 + nf * 16 + r15)) << 7) + (kq << 6) + swb);
    };
    auto mfma16 = [&](int mbase) {
        __builtin_amdgcn_s_setprio(1);
        #pragma unroll
        for (int mf = 0; mf < 4; ++mf)
            #pragma unroll
            for (int nf = 0; nf < 4; ++nf)
                acc[mbase + mf][nf] =
                    __builtin_amdgcn_mfma_f32_16x16x32_bf16(aF[mf], bF[nf], acc[mbase + mf][nf], 0, 0, 0);
        __builtin_amdgcn_s_setprio(0);
    };
    #define MIDSYNC() do { __builtin_amdgcn_s_barrier(); \
        asm volatile("s_waitcnt lgkmcnt(0)" ::: "memory"); \
        __builtin_amdgcn_sched_barrier(0); } while (0)
    #define ENDBAR() __builtin_amdgcn_s_barrier()

    const int NT = K >> 6;  // K-tiles of 64 (NT >= 2)

    // Prologue: T0.{A0,A1,B0,B1} + T1.{B0,B1}; vmcnt(4) -> T0 complete, T1.B in flight.
    stage_chunk64(Ab,               K, achunk(0, 0), t);
    stage_chunk64(Ab + halfA,       K, achunk(0, 1), t);
    stage_chunk64(Bb,               K, bchunk(0, 0), t);
    stage_chunk64(Bb + halfA,       K, bchunk(0, 1), t);
    stage_chunk64(Bb + 64,          K, bchunk(1, 0), t);
    stage_chunk64(Bb + halfA + 64,  K, bchunk(1, 1), t);
    asm volatile("s_waitcnt vmcnt(4)" ::: "memory");
    __builtin_amdgcn_s_barrier();

    for (int T = 0; T < NT; ++T) {
        const int p = T & 1, q = p ^ 1;
        const size_t ko1 = (size_t)(T + 1) << 6, ko2 = (size_t)(T + 2) << 6;
        char* myA = achunk(p, wm);
        char* myB = bchunk(p, wnh);
        // P1: (mf0-3, kq0); stage T+1.A0
        if (T + 1 < NT) stage_chunk64(Ab + ko1, K, achunk(q, 0), t);
        readA(myA, 0, 0);
        readB(myB, 0);
        if (T == NT - 1) asm volatile("s_waitcnt vmcnt(0)" ::: "memory");  // tail drain
        MIDSYNC();
        mfma16(0);
        ENDBAR();
        // P2: (mf4-7, kq0); stage T+1.A1; bF reused
        if (T + 1 < NT) stage_chunk64(Ab + halfA + ko1, K, achunk(q, 1), t);
        readA(myA, 4, 0);
        MIDSYNC();
        mfma16(4);
        ENDBAR();
        // P3: (mf4-7, kq1); no stage (B[p] still being read this phase)
        readA(myA, 4, 1);
        readB(myB, 1);
        MIDSYNC();
        mfma16(4);
        ENDBAR();
        // P4: (mf0-3, kq1); stage T+2.B0+B1; vmcnt(4) == tile T+1 fully landed
        if (T + 2 < NT) {
            stage_chunk64(Bb + ko2,         K, bchunk(p, 0), t);
            stage_chunk64(Bb + halfA + ko2, K, bchunk(p, 1), t);
        }
        readA(myA, 0, 1);
        asm volatile("s_waitcnt vmcnt(4)" ::: "memory");
        MIDSYNC();
        mfma16(0);
        ENDBAR();
    }

    // LoRA tail: one 32-wide K-step from TW [rows][32] / Bepi [cols][32].
    {
        const int q2 = NT & 1;
        stage_chunk32(TWb + (size_t)row0 * 32,          achunk(q2, 0), t);
        stage_chunk32(TWb + (size_t)(row0 + 128) * 32,  achunk(q2, 1), t);
        stage_chunk32(Bepi + (size_t)col0 * 32,         bchunk(q2, 0), t);
        stage_chunk32(Bepi + (size_t)(col0 + 128) * 32, bchunk(q2, 1), t);
        asm volatile("s_waitcnt vmcnt(0)" ::: "memory");
        __builtin_amdgcn_s_barrier();
        char* lA_ = achunk(q2, wm);
        char* lB_ = bchunk(q2, wnh);
        #pragma unroll
        for (int nf = 0; nf < 4; ++nf)
            bF[nf] = *(const bf16x8*)(lB_ + (((wn & 1) * 64 + nf * 16 + r15) << 6) + swb);
        #pragma unroll
        for (int i = 0; i < 4; ++i)
            aF[i] = *(const bf16x8*)(lA_ + ((i * 16 + r15) << 6) + swb);
        asm volatile("s_waitcnt lgkmcnt(0)" ::: "memory");
        __builtin_amdgcn_sched_barrier(0);
        mfma16(0);
        #pragma unroll
        for (int i = 0; i < 4; ++i)
            aF[i] = *(const bf16x8*)(lA_ + (((i + 4) * 16 + r15) << 6) + swb);
        asm volatile("s_waitcnt lgkmcnt(0)" ::: "memory");
        __builtin_amdgcn_sched_barrier(0);
        mfma16(4);
    }

    // Epilogue: bias + relu, bf16 store
    const int orow = row0 + wm * 128 + (lane >> 4) * 4;
    const int ocol = col0 + wn * 64 + r15;
    #pragma unroll
    for (int nf = 0; nf < 4; ++nf) {
        const int col = ocol + nf * 16;
        const float bn = bias[col];
        #pragma unroll
        for (int mf = 0; mf < 8; ++mf) {
            const int rbase = orow + mf * 16;
            #pragma unroll
            for (int i = 0; i < 4; ++i) {
                const float v = fmaxf(acc[mf][nf][i] + bn, 0.f);
                outp[(size_t)(rbase + i) * N + col] = (__bf16)v;
            }
        }
    }
    #undef MIDSYNC
    #undef ENDBAR
}

// ---------------- old 128x128 GEMM (kept for layer 3: N=512)
#define BM 128
#define BN 128
#define BK 32

template<bool OUT_F32>
__global__ void __launch_bounds__(256) gemm_lora(
    const bf16_t* __restrict__ Abuf, const bf16_t* __restrict__ Wbuf,
    const float* __restrict__ bias, const bf16_t* __restrict__ TWb,
    const bf16_t* __restrict__ Bepi, void* __restrict__ outp,
    const int N, const int K)
{
    __shared__ bf16_t lA[BM * BK];
    __shared__ bf16_t lB[BN * BK];
    const int t = threadIdx.x;
    const int row0 = blockIdx.y * BM;
    const int col0 = blockIdx.x * BN;
    const int wid = t >> 6, lane = t & 63;
    const int wr = wid >> 1, wc = wid & 1;
    const int ln15 = lane & 15, kg = (lane >> 4) * 8;
    const int srow = t >> 2, sg8 = (t & 3) * 8;
    const bf16_t* gA = Abuf + (size_t)(row0 + srow) * K + sg8;
    const bf16_t* gB = Wbuf + (size_t)(col0 + srow) * K + sg8;
    bf16_t* ldA  = &lA[t * 8];
    bf16_t* ldA2 = &lA[2048 + t * 8];
    bf16_t* ldB  = &lB[t * 8];
    bf16_t* ldB2 = &lB[2048 + t * 8];
    f32x4 acc[4][4] = {};
    const int aoff = (wr * 64 + ln15) * BK + kg;
    const int boff = (wc * 64 + ln15) * BK + kg;

    auto compute_tile = [&]() {
        bf16x8 af[4], bfr[4];
        #pragma unroll
        for (int m = 0; m < 4; ++m) af[m] = *(const bf16x8*)&lA[aoff + m * 16 * BK];
        #pragma unroll
        for (int n = 0; n < 4; ++n) bfr[n] = *(const bf16x8*)&lB[boff + n * 16 * BK];
        #pragma unroll
        for (int m = 0; m < 4; ++m)
            #pragma unroll
            for (int n = 0; n < 4; ++n)
                acc[m][n] = __builtin_amdgcn_mfma_f32_16x16x32_bf16(af[m], bfr[n], acc[m][n], 0, 0, 0);
    };

    const size_t half = (size_t)64 * K;
    const int nk = K / BK;
    for (int kt = 0; kt < nk; ++kt) {
        gload_lds16(gA + kt * BK, ldA);
        gload_lds16(gA + half + kt * BK, ldA2);
        gload_lds16(gB + kt * BK, ldB);
        gload_lds16(gB + half + kt * BK, ldB2);
        __syncthreads();
        compute_tile();
        __syncthreads();
    }
    gload_lds16(TWb + (size_t)(row0 + srow) * 32 + sg8, ldA);
    gload_lds16(TWb + (size_t)(row0 + 64 + srow) * 32 + sg8, ldA2);
    gload_lds16(Bepi + (size_t)(col0 + srow) * 32 + sg8, ldB);
    gload_lds16(Bepi + (size_t)(col0 + 64 + srow) * 32 + sg8, ldB2);
    __syncthreads();
    compute_tile();

    const int orow = row0 + wr * 64 + (lane >> 4) * 4;
    const int ocol = col0 + wc * 64 + ln15;
    #pragma unroll
    for (int n = 0; n < 4; ++n) {
        const int col = ocol + n * 16;
        const float bn = bias[col];
        #pragma unroll
        for (int m = 0; m < 4; ++m) {
            const int rbase = orow + m * 16;
            #pragma unroll
            for (int i = 0; i < 4; ++i) {
                const float v = fmaxf(acc[m][n][i] + bn, 0.f);
                if constexpr (OUT_F32)
                    ((float*)outp)[(size_t)(rbase + i) * N + col] = v;
                else
                    ((bf16_t*)outp)[(size_t)(rbase + i) * N + col] = (__bf16)v;
            }
        }
    }
}

extern "C" void kernel_launch(void* const* d_in, const int* in_sizes, int n_in,
                              void* d_out, int out_size, void* d_ws, size_t ws_size,
                              hipStream_t stream)
{
    const float* x    = (const float*)d_in[0];
    const int*   dom  = (const int*)d_in[1];
    const float* W1   = (const float*)d_in[2];  const float* b1  = (const float*)d_in[3];
    const float* W2   = (const float*)d_in[4];  const float* b2  = (const float*)d_in[5];
    const float* W3   = (const float*)d_in[6];  const float* b3  = (const float*)d_in[7];
    const float* A1   = (const float*)d_in[8];  const float* B1  = (const float*)d_in[9];
    const float* A2   = (const float*)d_in[10]; const float* B2  = (const float*)d_in[11];
    const float* A3   = (const float*)d_in[12]; const float* B3  = (const float*)d_in[13];
    const float* dome = (const float*)d_in[14]; const float* lpos = (const float*)d_in[15];
    const float* Wi1  = (const float*)d_in[16]; const float* bi1 = (const float*)d_in[17];
    const float* Wi2  = (const float*)d_in[18]; const float* bi2 = (const float*)d_in[19];
    const float* Wa1  = (const float*)d_in[20]; const float* ba1 = (const float*)d_in[21];
    const float* Wa2  = (const float*)d_in[22]; const float* ba2 = (const float*)d_in[23];
    const float* gate = (const float*)d_in[24]; const float* Rb  = (const float*)d_in[25];
    (void)in_sizes; (void)n_in; (void)out_size; (void)ws_size;

    constexpr int Bsz = 16384, D0 = 2048, D1 = 2048, D2 = 1024, D3 = 512;

    char* ws = (char*)d_ws;
    size_t off = 0;
    auto alloc = [&](size_t bytes) -> void* {
        void* p = ws + off;
        off = (off + bytes + 255) & ~(size_t)255;
        return p;
    };
    float*  salpha = (float*) alloc(8 * 3 * 4 * sizeof(float));
    bf16_t* W1b = (bf16_t*)alloc((size_t)D1 * D0 * 2);
    bf16_t* W2b = (bf16_t*)alloc((size_t)D2 * D1 * 2);
    bf16_t* W3b = (bf16_t*)alloc((size_t)D3 * D2 * 2);
    bf16_t* Ac1 = (bf16_t*)alloc((size_t)32 * D0 * 2);
    bf16_t* Ac2 = (bf16_t*)alloc((size_t)32 * D1 * 2);
    bf16_t* Ac3 = (bf16_t*)alloc((size_t)32 * D2 * 2);
    bf16_t* Be1 = (bf16_t*)alloc((size_t)D1 * 32 * 2);
    bf16_t* Be2 = (bf16_t*)alloc((size_t)D2 * 32 * 2);
    bf16_t* Be3 = (bf16_t*)alloc((size_t)D3 * 32 * 2);
    bf16_t* TWb = (bf16_t*)alloc((size_t)Bsz * 32 * 2);
    bf16_t* xb  = (bf16_t*)alloc((size_t)Bsz * D0 * 2);
    bf16_t* h1b = (bf16_t*)alloc((size_t)Bsz * D1 * 2);
    bf16_t* h2b = xb;  // xb dead after layer-1 GEMM

    routing_kernel<<<1, 256, 0, stream>>>(dome, lpos, Wi1, bi1, Wi2, bi2,
                                          Wa1, ba1, Wa2, ba2, gate, Rb, salpha);

    cvt_f32_bf16<<<(D1 * D0 / 4 + 255) / 256, 256, 0, stream>>>(W1, W1b, D1 * D0 / 4);
    cvt_f32_bf16<<<(D2 * D1 / 4 + 255) / 256, 256, 0, stream>>>(W2, W2b, D2 * D1 / 4);
    cvt_f32_bf16<<<(D3 * D2 / 4 + 255) / 256, 256, 0, stream>>>(W3, W3b, D3 * D2 / 4);
    cvt_f32_bf16<<<(32 * D0 / 4 + 255) / 256, 256, 0, stream>>>(A1, Ac1, 32 * D0 / 4);
    cvt_f32_bf16<<<(32 * D1 / 4 + 255) / 256, 256, 0, stream>>>(A2, Ac2, 32 * D1 / 4);
    cvt_f32_bf16<<<(32 * D2 / 4 + 255) / 256, 256, 0, stream>>>(A3, Ac3, 32 * D2 / 4);
    bepi_cvt<<<(D1 * 32 + 255) / 256, 256, 0, stream>>>(B1, Be1, D1);
    bepi_cvt<<<(D2 * 32 + 255) / 256, 256, 0, stream>>>(B2, Be2, D2);
    bepi_cvt<<<(D3 * 32 + 255) / 256, 256, 0, stream>>>(B3, Be3, D3);

    // layer 1: 256^2 8-phase (grid 64x8 = 512 blocks)
    tw_kernel<true><<<Bsz / 64, 256, 0, stream>>>(x, xb, Ac1, salpha, dom, 0, D0, TWb);
    gemm_lora8<<<(Bsz / 256) * (D1 / 256), 512, 0, stream>>>(xb, W1b, b1, TWb, Be1, h1b, D1, D0, D1 / 256);
    // layer 2: 256^2 8-phase (grid 64x4 = 256 blocks)
    tw_kernel<false><<<Bsz / 64, 256, 0, stream>>>(h1b, nullptr, Ac2, salpha, dom, 1, D1, TWb);
    gemm_lora8<<<(Bsz / 256) * (D2 / 256), 512, 0, stream>>>(h1b, W2b, b2, TWb, Be2, h2b, D2, D1, D2 / 256);
    // layer 3 (f32 out, old 128^2 kernel: grid 4x128)
    tw_kernel<false><<<Bsz / 64, 256, 0, stream>>>(h2b, nullptr, Ac3, salpha, dom, 2, D2, TWb);
    gemm_lora<true><<<dim3(D3 / BN, Bsz / BM), 256, 0, stream>>>(h2b, W3b, b3, TWb, Be3, d_out, D3, D2);
}

// Round 5
// 418.344 us; speedup vs baseline: 1.2402x; 1.0382x over previous
//
#include <hip/hip_runtime.h>

typedef __bf16 bf16_t;
typedef __bf16 bf16x8 __attribute__((ext_vector_type(8)));
typedef __bf16 bf16x4_v __attribute__((ext_vector_type(4)));
typedef float f32x4 __attribute__((ext_vector_type(4)));

#define AS1 __attribute__((address_space(1)))
#define AS3 __attribute__((address_space(3)))

__device__ __forceinline__ void gload_lds16(const void* g, void* l) {
    __builtin_amdgcn_global_load_lds((AS1 void*)(void*)g, (AS3 void*)l, 16, 0, 0);
}

// ---------------- routing: salpha[m][l][e] = zeta_agg[m][l] * alpha_agg[m][l][e]
__global__ void routing_kernel(
    const float* __restrict__ dom_emb, const float* __restrict__ layer_pos,
    const float* __restrict__ Wi1, const float* __restrict__ bi1,
    const float* __restrict__ Wi2, const float* __restrict__ bi2,
    const float* __restrict__ Wa1, const float* __restrict__ ba1,
    const float* __restrict__ Wa2, const float* __restrict__ ba2,
    const float* __restrict__ gate_logits, const float* __restrict__ R_benefit,
    float* __restrict__ salpha)
{
    constexpr int M = 8, L = 3, E = 4, H = 64;
    __shared__ float zl[M * L];
    __shared__ float al[M * L][E];
    __shared__ float zeta_all[M][L];
    __shared__ float alpha_all[M][L][E];
    const int t = threadIdx.x;
    const int ml = t >> 3, js = t & 7;
    if (ml < M * L) {
        const int m = ml / L, l = ml % L;
        float zacc = 0.f;
        float aacc[E] = {0.f, 0.f, 0.f, 0.f};
        for (int jj = 0; jj < 8; ++jj) {
            const int j = js * 8 + jj;
            float hz = bi1[j], ha = ba1[j];
            for (int i = 0; i < H; ++i) {
                const float de = dom_emb[m * H + i];
                const float lp = layer_pos[l * H + i];
                hz += de * Wi1[j * 2 * H + i] + lp * Wi1[j * 2 * H + H + i];
                ha += de * Wa1[j * 2 * H + i] + lp * Wa1[j * 2 * H + H + i];
            }
            hz = fmaxf(hz, 0.f); ha = fmaxf(ha, 0.f);
            zacc += hz * Wi2[j];
            for (int e = 0; e < E; ++e) aacc[e] += ha * Wa2[e * H + j];
        }
        #pragma unroll
        for (int off = 4; off >= 1; off >>= 1) {
            zacc += __shfl_down(zacc, off, 8);
            for (int e = 0; e < E; ++e) aacc[e] += __shfl_down(aacc[e], off, 8);
        }
        if (js == 0) {
            zl[ml] = zacc + bi2[0];
            for (int e = 0; e < E; ++e) al[ml][e] = aacc[e] + ba2[e];
        }
    }
    __syncthreads();
    if (t < M) {
        const int m = t;
        float v[3] = { zl[m * L + 0], zl[m * L + 1], zl[m * L + 2] };
        int di = 0; float dv = v[0];
        for (int i = 1; i < 3; ++i) if (v[i] <= dv) { dv = v[i]; di = i; }
        float mx = -1e30f;
        for (int i = 0; i < 3; ++i) if (i != di) mx = fmaxf(mx, v[i]);
        float s = 0.f, ev[3];
        for (int i = 0; i < 3; ++i) { ev[i] = (i == di) ? 0.f : expf(v[i] - mx); s += ev[i]; }
        for (int i = 0; i < 3; ++i) zeta_all[m][i] = ev[i] / s;
        for (int l = 0; l < L; ++l) {
            float a[4];
            for (int e = 0; e < 4; ++e) a[e] = al[m * L + l][e];
            int i1 = 0;
            for (int e = 1; e < 4; ++e) if (a[e] > a[i1]) i1 = e;
            int i2 = -1;
            for (int e = 0; e < 4; ++e) { if (e == i1) continue; if (i2 < 0 || a[e] > a[i2]) i2 = e; }
            const float mx2 = fmaxf(a[i1], a[i2]);
            const float e1 = expf(a[i1] - mx2), e2 = expf(a[i2] - mx2);
            const float ss = e1 + e2;
            for (int e = 0; e < 4; ++e) alpha_all[m][l][e] = 0.f;
            alpha_all[m][l][i1] = e1 / ss;
            alpha_all[m][l][i2] = e2 / ss;
        }
    }
    __syncthreads();
    if (t < M) {
        const int m = t;
        float Rrow[8]; float rs = 0.f;
        for (int n = 0; n < M; ++n) {
            const float g = gate_logits[m * M + n];
            const float rr = log1pf(expf(g)) * R_benefit[m * M + n];
            Rrow[n] = rr; rs += rr;
        }
        rs = fmaxf(rs, 1e-12f);
        for (int l = 0; l < L; ++l) {
            float zag = 0.f, aag[4] = {0.f, 0.f, 0.f, 0.f};
            for (int n = 0; n < M; ++n) {
                const float w = Rrow[n] / rs;
                zag += w * zeta_all[n][l];
                for (int e = 0; e < 4; ++e) aag[e] += w * alpha_all[n][l][e];
            }
            for (int e = 0; e < 4; ++e) salpha[(m * L + l) * 4 + e] = zag * aag[e];
        }
    }
}

// ---------------- f32 -> bf16 flat convert
__global__ void cvt_f32_bf16(const float* __restrict__ in, bf16_t* __restrict__ out, const int n4) {
    const int i = blockIdx.x * 256 + threadIdx.x;
    if (i < n4) {
        const float4 v = ((const float4*)in)[i];
        bf16x4_v o;
        o[0] = (__bf16)v.x; o[1] = (__bf16)v.y; o[2] = (__bf16)v.z; o[3] = (__bf16)v.w;
        ((bf16x4_v*)out)[i] = o;
    }
}

// B [E][Dout][r] f32 -> Bepi [Dout][32] bf16, c = e*8+r
__global__ void bepi_cvt(const float* __restrict__ Bsrc, bf16_t* __restrict__ out, const int Dout) {
    const int idx = blockIdx.x * 256 + threadIdx.x;
    if (idx < Dout * 32) {
        const int o = idx >> 5, c = idx & 31, e = c >> 3, r = c & 7;
        out[idx] = (__bf16)Bsrc[((size_t)e * Dout + o) * 8 + r];
    }
}

// ---------------- TW[b][c] = (sum_k h[b][k]*Acat[c][k]) * salpha[dom[b]][layer][c>>3]
template<bool F32IN>
__global__ void __launch_bounds__(256) tw_kernel(
    const void* __restrict__ hin, bf16_t* __restrict__ xb_out,
    const bf16_t* __restrict__ Acat, const float* __restrict__ salpha,
    const int* __restrict__ dom, const int layer, const int K,
    bf16_t* __restrict__ TWb)
{
    const int t = threadIdx.x, wid = t >> 6, lane = t & 63;
    const int rb = blockIdx.x * 64 + wid * 16;
    const int ln15 = lane & 15, kg = (lane >> 4) * 8;
    const int row = rb + ln15;
    f32x4 acc0 = {0.f, 0.f, 0.f, 0.f}, acc1 = {0.f, 0.f, 0.f, 0.f};
    const bf16_t* pa0 = Acat + (size_t)ln15 * K + kg;
    const bf16_t* pa1 = pa0 + (size_t)16 * K;
    for (int k0 = 0; k0 < K; k0 += 32) {
        bf16x8 a;
        if constexpr (F32IN) {
            const float* px = (const float*)hin + (size_t)row * K + k0 + kg;
            const float4 x0 = *(const float4*)px;
            const float4 x1 = *(const float4*)(px + 4);
            a[0] = (__bf16)x0.x; a[1] = (__bf16)x0.y; a[2] = (__bf16)x0.z; a[3] = (__bf16)x0.w;
            a[4] = (__bf16)x1.x; a[5] = (__bf16)x1.y; a[6] = (__bf16)x1.z; a[7] = (__bf16)x1.w;
            *(bf16x8*)(xb_out + (size_t)row * K + k0 + kg) = a;
        } else {
            a = *(const bf16x8*)((const bf16_t*)hin + (size_t)row * K + k0 + kg);
        }
        const bf16x8 b0 = *(const bf16x8*)(pa0 + k0);
        const bf16x8 b1 = *(const bf16x8*)(pa1 + k0);
        acc0 = __builtin_amdgcn_mfma_f32_16x16x32_bf16(a, b0, acc0, 0, 0, 0);
        acc1 = __builtin_amdgcn_mfma_f32_16x16x32_bf16(a, b1, acc1, 0, 0, 0);
    }
    const int rbase = rb + (lane >> 4) * 4;
    #pragma unroll
    for (int i = 0; i < 4; ++i) {
        const int r2 = rbase + i;
        const int d = dom[r2];
        const float* sa = salpha + (d * 3 + layer) * 4;
        const float s0 = sa[ln15 >> 3];
        const float s1 = sa[2 + (ln15 >> 3)];
        TWb[(size_t)r2 * 32 + ln15]      = (__bf16)(acc0[i] * s0);
        TWb[(size_t)r2 * 32 + 16 + ln15] = (__bf16)(acc1[i] * s1);
    }
}

// ================= 256x256 8-phase GEMM + fused LoRA K-step =================
// LDS chunk = 16KB = [kh:2][row:128][32 k] bf16 -> 64-BYTE rows (16-bank stagger
// between odd/even rows). Swizzle: 16B-slot bit1 ^= row bit3. A wave's fragment
// read (16 rows x 4 slots, fixed kh) then splits into 8 classes of 8 lanes, one
// per 4-bank group, covering all 32 banks -> conflict-free (8-cyc ideal drain).
// R4 failure root-cause: previous 128B rows put every row at bank 0 -> only 16
// banks touched regardless of XOR. Staged via inverse-permuted global source +
// linear LDS dest (involution, rule #21).
// Schedule (unchanged): P1->T+1.A0, P2->T+1.A1, P4->T+2.B0+B1; vmcnt(4) at P4.

__device__ __forceinline__ void stage_chunk64(const bf16_t* g, int ldK, char* chunk, int t) {
    #pragma unroll
    for (int w = 0; w < 2; ++w) {                    // w = k-half plane (8KB each)
        const int row = t >> 2;
        const int sl = t & 3;
        const int src = sl ^ (((row >> 3) & 1) << 1);  // inverse swizzle on source slot
        gload_lds16(g + (size_t)row * ldK + w * 32 + src * 8, chunk + w * 8192 + t * 16);
    }
}

// LoRA chunk: [128 rows][32 k] = 64B rows, 8KB, one sweep, same swizzle.
__device__ __forceinline__ void stage_chunk32(const bf16_t* g, char* chunk, int t) {
    const int row = t >> 2;
    const int sl = t & 3;
    const int src = sl ^ (((row >> 3) & 1) << 1);
    gload_lds16(g + (size_t)row * 32 + src * 8, chunk + t * 16);
}

__global__ void __launch_bounds__(512, 2) gemm_lora8(
    const bf16_t* __restrict__ Abuf, const bf16_t* __restrict__ Wbuf,
    const float* __restrict__ bias, const bf16_t* __restrict__ TWb,
    const bf16_t* __restrict__ Bepi, bf16_t* __restrict__ outp,
    const int N, const int K, const int nwg_n)
{
    __shared__ __align__(1024) char lds[131072];
    const int t = threadIdx.x;
    const int wid = t >> 6, lane = t & 63;
    const int wm = wid >> 2, wn = wid & 3, wnh = wn >> 1;
    // T1: bijective XCD swizzle (grid % 8 == 0)
    const int cpx = gridDim.x >> 3;
    const int wg = (blockIdx.x & 7) * cpx + (blockIdx.x >> 3);
    const int row0 = (wg / nwg_n) * 256, col0 = (wg % nwg_n) * 256;

    const int r15 = lane & 15;
    // slot = (lane>>4) ^ 2*rowbit3; rowbit3 == lane bit3 for all fragment reads
    const int swb = ((lane >> 4) ^ (((lane >> 3) & 1) << 1)) << 4;

    auto achunk = [&](int p, int c) -> char* { return lds + (((p << 1) + c) << 14); };
    auto bchunk = [&](int p, int c) -> char* { return lds + 65536 + (((p << 1) + c) << 14); };

    const bf16_t* Ab = Abuf + (size_t)row0 * K;
    const bf16_t* Bb = Wbuf + (size_t)col0 * K;
    const size_t halfA = (size_t)128 * K;

    f32x4 acc[8][4] = {};
    bf16x8 aF[4], bF[4];

    auto readA = [&](char* c, int mbase, int kq) {
        #pragma unroll
        for (int i = 0; i < 4; ++i)
            aF[i] = *(const bf16x8*)(c + (kq << 13) + (((mbase + i) * 16 + r15) << 6) + swb);
    };
    auto readB = [&](char* c, int kq) {
        #pragma unroll
        for (int nf = 0; nf < 4; ++nf)
            bF[nf] = *(const bf16x8*)(c + (kq << 13) + (((wn & 1) * 64 + nf * 16 + r15) << 6) + swb);
    };
    auto mfma16 = [&](int mbase) {
        __builtin_amdgcn_s_setprio(1);
        #pragma unroll
        for (int mf = 0; mf < 4; ++mf)
            #pragma unroll
            for (int nf = 0; nf < 4; ++nf)
                acc[mbase + mf][nf] =
                    __builtin_amdgcn_mfma_f32_16x16x32_bf16(aF[mf], bF[nf], acc[mbase + mf][nf], 0, 0, 0);
        __builtin_amdgcn_s_setprio(0);
    };
    #define MIDSYNC() do { __builtin_amdgcn_s_barrier(); \
        asm volatile("s_waitcnt lgkmcnt(0)" ::: "memory"); \
        __builtin_amdgcn_sched_barrier(0); } while (0)
    #define ENDBAR() __builtin_amdgcn_s_barrier()

    const int NT = K >> 6;  // K-tiles of 64 (NT >= 2)

    // Prologue: T0.{A0,A1,B0,B1} + T1.{B0,B1}; vmcnt(4) -> T0 complete, T1.B in flight.
    stage_chunk64(Ab,               K, achunk(0, 0), t);
    stage_chunk64(Ab + halfA,       K, achunk(0, 1), t);
    stage_chunk64(Bb,               K, bchunk(0, 0), t);
    stage_chunk64(Bb + halfA,       K, bchunk(0, 1), t);
    stage_chunk64(Bb + 64,          K, bchunk(1, 0), t);
    stage_chunk64(Bb + halfA + 64,  K, bchunk(1, 1), t);
    asm volatile("s_waitcnt vmcnt(4)" ::: "memory");
    __builtin_amdgcn_s_barrier();

    for (int T = 0; T < NT; ++T) {
        const int p = T & 1, q = p ^ 1;
        const size_t ko1 = (size_t)(T + 1) << 6, ko2 = (size_t)(T + 2) << 6;
        char* myA = achunk(p, wm);
        char* myB = bchunk(p, wnh);
        // P1: (mf0-3, kq0); stage T+1.A0
        if (T + 1 < NT) stage_chunk64(Ab + ko1, K, achunk(q, 0), t);
        readA(myA, 0, 0);
        readB(myB, 0);
        if (T == NT - 1) asm volatile("s_waitcnt vmcnt(0)" ::: "memory");  // tail drain
        MIDSYNC();
        mfma16(0);
        ENDBAR();
        // P2: (mf4-7, kq0); stage T+1.A1; bF reused
        if (T + 1 < NT) stage_chunk64(Ab + halfA + ko1, K, achunk(q, 1), t);
        readA(myA, 4, 0);
        MIDSYNC();
        mfma16(4);
        ENDBAR();
        // P3: (mf4-7, kq1); no stage (B[p] still being read this phase)
        readA(myA, 4, 1);
        readB(myB, 1);
        MIDSYNC();
        mfma16(4);
        ENDBAR();
        // P4: (mf0-3, kq1); stage T+2.B0+B1; vmcnt(4) == tile T+1 fully landed
        if (T + 2 < NT) {
            stage_chunk64(Bb + ko2,         K, bchunk(p, 0), t);
            stage_chunk64(Bb + halfA + ko2, K, bchunk(p, 1), t);
        }
        readA(myA, 0, 1);
        asm volatile("s_waitcnt vmcnt(4)" ::: "memory");
        MIDSYNC();
        mfma16(0);
        ENDBAR();
    }

    // LoRA tail: one 32-wide K-step from TW [rows][32] / Bepi [cols][32].
    {
        const int q2 = NT & 1;
        stage_chunk32(TWb + (size_t)row0 * 32,          achunk(q2, 0), t);
        stage_chunk32(TWb + (size_t)(row0 + 128) * 32,  achunk(q2, 1), t);
        stage_chunk32(Bepi + (size_t)col0 * 32,         bchunk(q2, 0), t);
        stage_chunk32(Bepi + (size_t)(col0 + 128) * 32, bchunk(q2, 1), t);
        asm volatile("s_waitcnt vmcnt(0)" ::: "memory");
        __builtin_amdgcn_s_barrier();
        char* lA_ = achunk(q2, wm);
        char* lB_ = bchunk(q2, wnh);
        #pragma unroll
        for (int nf = 0; nf < 4; ++nf)
            bF[nf] = *(const bf16x8*)(lB_ + (((wn & 1) * 64 + nf * 16 + r15) << 6) + swb);
        #pragma unroll
        for (int i = 0; i < 4; ++i)
            aF[i] = *(const bf16x8*)(lA_ + ((i * 16 + r15) << 6) + swb);
        asm volatile("s_waitcnt lgkmcnt(0)" ::: "memory");
        __builtin_amdgcn_sched_barrier(0);
        mfma16(0);
        #pragma unroll
        for (int i = 0; i < 4; ++i)
            aF[i] = *(const bf16x8*)(lA_ + (((i + 4) * 16 + r15) << 6) + swb);
        asm volatile("s_waitcnt lgkmcnt(0)" ::: "memory");
        __builtin_amdgcn_sched_barrier(0);
        mfma16(4);
    }

    // Epilogue: bias + relu, bf16 store
    const int orow = row0 + wm * 128 + (lane >> 4) * 4;
    const int ocol = col0 + wn * 64 + r15;
    #pragma unroll
    for (int nf = 0; nf < 4; ++nf) {
        const int col = ocol + nf * 16;
        const float bn = bias[col];
        #pragma unroll
        for (int mf = 0; mf < 8; ++mf) {
            const int rbase = orow + mf * 16;
            #pragma unroll
            for (int i = 0; i < 4; ++i) {
                const float v = fmaxf(acc[mf][nf][i] + bn, 0.f);
                outp[(size_t)(rbase + i) * N + col] = (__bf16)v;
            }
        }
    }
    #undef MIDSYNC
    #undef ENDBAR
}

// ---------------- old 128x128 GEMM (kept for layer 3: N=512)
#define BM 128
#define BN 128
#define BK 32

template<bool OUT_F32>
__global__ void __launch_bounds__(256) gemm_lora(
    const bf16_t* __restrict__ Abuf, const bf16_t* __restrict__ Wbuf,
    const float* __restrict__ bias, const bf16_t* __restrict__ TWb,
    const bf16_t* __restrict__ Bepi, void* __restrict__ outp,
    const int N, const int K)
{
    __shared__ bf16_t lA[BM * BK];
    __shared__ bf16_t lB[BN * BK];
    const int t = threadIdx.x;
    const int row0 = blockIdx.y * BM;
    const int col0 = blockIdx.x * BN;
    const int wid = t >> 6, lane = t & 63;
    const int wr = wid >> 1, wc = wid & 1;
    const int ln15 = lane & 15, kg = (lane >> 4) * 8;
    const int srow = t >> 2, sg8 = (t & 3) * 8;
    const bf16_t* gA = Abuf + (size_t)(row0 + srow) * K + sg8;
    const bf16_t* gB = Wbuf + (size_t)(col0 + srow) * K + sg8;
    bf16_t* ldA  = &lA[t * 8];
    bf16_t* ldA2 = &lA[2048 + t * 8];
    bf16_t* ldB  = &lB[t * 8];
    bf16_t* ldB2 = &lB[2048 + t * 8];
    f32x4 acc[4][4] = {};
    const int aoff = (wr * 64 + ln15) * BK + kg;
    const int boff = (wc * 64 + ln15) * BK + kg;

    auto compute_tile = [&]() {
        bf16x8 af[4], bfr[4];
        #pragma unroll
        for (int m = 0; m < 4; ++m) af[m] = *(const bf16x8*)&lA[aoff + m * 16 * BK];
        #pragma unroll
        for (int n = 0; n < 4; ++n) bfr[n] = *(const bf16x8*)&lB[boff + n * 16 * BK];
        #pragma unroll
        for (int m = 0; m < 4; ++m)
            #pragma unroll
            for (int n = 0; n < 4; ++n)
                acc[m][n] = __builtin_amdgcn_mfma_f32_16x16x32_bf16(af[m], bfr[n], acc[m][n], 0, 0, 0);
    };

    const size_t half = (size_t)64 * K;
    const int nk = K / BK;
    for (int kt = 0; kt < nk; ++kt) {
        gload_lds16(gA + kt * BK, ldA);
        gload_lds16(gA + half + kt * BK, ldA2);
        gload_lds16(gB + kt * BK, ldB);
        gload_lds16(gB + half + kt * BK, ldB2);
        __syncthreads();
        compute_tile();
        __syncthreads();
    }
    gload_lds16(TWb + (size_t)(row0 + srow) * 32 + sg8, ldA);
    gload_lds16(TWb + (size_t)(row0 + 64 + srow) * 32 + sg8, ldA2);
    gload_lds16(Bepi + (size_t)(col0 + srow) * 32 + sg8, ldB);
    gload_lds16(Bepi + (size_t)(col0 + 64 + srow) * 32 + sg8, ldB2);
    __syncthreads();
    compute_tile();

    const int orow = row0 + wr * 64 + (lane >> 4) * 4;
    const int ocol = col0 + wc * 64 + ln15;
    #pragma unroll
    for (int n = 0; n < 4; ++n) {
        const int col = ocol + n * 16;
        const float bn = bias[col];
        #pragma unroll
        for (int m = 0; m < 4; ++m) {
            const int rbase = orow + m * 16;
            #pragma unroll
            for (int i = 0; i < 4; ++i) {
                const float v = fmaxf(acc[m][n][i] + bn, 0.f);
                if constexpr (OUT_F32)
                    ((float*)outp)[(size_t)(rbase + i) * N + col] = v;
                else
                    ((bf16_t*)outp)[(size_t)(rbase + i) * N + col] = (__bf16)v;
            }
        }
    }
}

extern "C" void kernel_launch(void* const* d_in, const int* in_sizes, int n_in,
                              void* d_out, int out_size, void* d_ws, size_t ws_size,
                              hipStream_t stream)
{
    const float* x    = (const float*)d_in[0];
    const int*   dom  = (const int*)d_in[1];
    const float* W1   = (const float*)d_in[2];  const float* b1  = (const float*)d_in[3];
    const float* W2   = (const float*)d_in[4];  const float* b2  = (const float*)d_in[5];
    const float* W3   = (const float*)d_in[6];  const float* b3  = (const float*)d_in[7];
    const float* A1   = (const float*)d_in[8];  const float* B1  = (const float*)d_in[9];
    const float* A2   = (const float*)d_in[10]; const float* B2  = (const float*)d_in[11];
    const float* A3   = (const float*)d_in[12]; const float* B3  = (const float*)d_in[13];
    const float* dome = (const float*)d_in[14]; const float* lpos = (const float*)d_in[15];
    const float* Wi1  = (const float*)d_in[16]; const float* bi1 = (const float*)d_in[17];
    const float* Wi2  = (const float*)d_in[18]; const float* bi2 = (const float*)d_in[19];
    const float* Wa1  = (const float*)d_in[20]; const float* ba1 = (const float*)d_in[21];
    const float* Wa2  = (const float*)d_in[22]; const float* ba2 = (const float*)d_in[23];
    const float* gate = (const float*)d_in[24]; const float* Rb  = (const float*)d_in[25];
    (void)in_sizes; (void)n_in; (void)out_size; (void)ws_size;

    constexpr int Bsz = 16384, D0 = 2048, D1 = 2048, D2 = 1024, D3 = 512;

    char* ws = (char*)d_ws;
    size_t off = 0;
    auto alloc = [&](size_t bytes) -> void* {
        void* p = ws + off;
        off = (off + bytes + 255) & ~(size_t)255;
        return p;
    };
    float*  salpha = (float*) alloc(8 * 3 * 4 * sizeof(float));
    bf16_t* W1b = (bf16_t*)alloc((size_t)D1 * D0 * 2);
    bf16_t* W2b = (bf16_t*)alloc((size_t)D2 * D1 * 2);
    bf16_t* W3b = (bf16_t*)alloc((size_t)D3 * D2 * 2);
    bf16_t* Ac1 = (bf16_t*)alloc((size_t)32 * D0 * 2);
    bf16_t* Ac2 = (bf16_t*)alloc((size_t)32 * D1 * 2);
    bf16_t* Ac3 = (bf16_t*)alloc((size_t)32 * D2 * 2);
    bf16_t* Be1 = (bf16_t*)alloc((size_t)D1 * 32 * 2);
    bf16_t* Be2 = (bf16_t*)alloc((size_t)D2 * 32 * 2);
    bf16_t* Be3 = (bf16_t*)alloc((size_t)D3 * 32 * 2);
    bf16_t* TWb = (bf16_t*)alloc((size_t)Bsz * 32 * 2);
    bf16_t* xb  = (bf16_t*)alloc((size_t)Bsz * D0 * 2);
    bf16_t* h1b = (bf16_t*)alloc((size_t)Bsz * D1 * 2);
    bf16_t* h2b = xb;  // xb dead after layer-1 GEMM

    routing_kernel<<<1, 256, 0, stream>>>(dome, lpos, Wi1, bi1, Wi2, bi2,
                                          Wa1, ba1, Wa2, ba2, gate, Rb, salpha);

    cvt_f32_bf16<<<(D1 * D0 / 4 + 255) / 256, 256, 0, stream>>>(W1, W1b, D1 * D0 / 4);
    cvt_f32_bf16<<<(D2 * D1 / 4 + 255) / 256, 256, 0, stream>>>(W2, W2b, D2 * D1 / 4);
    cvt_f32_bf16<<<(D3 * D2 / 4 + 255) / 256, 256, 0, stream>>>(W3, W3b, D3 * D2 / 4);
    cvt_f32_bf16<<<(32 * D0 / 4 + 255) / 256, 256, 0, stream>>>(A1, Ac1, 32 * D0 / 4);
    cvt_f32_bf16<<<(32 * D1 / 4 + 255) / 256, 256, 0, stream>>>(A2, Ac2, 32 * D1 / 4);
    cvt_f32_bf16<<<(32 * D2 / 4 + 255) / 256, 256, 0, stream>>>(A3, Ac3, 32 * D2 / 4);
    bepi_cvt<<<(D1 * 32 + 255) / 256, 256, 0, stream>>>(B1, Be1, D1);
    bepi_cvt<<<(D2 * 32 + 255) / 256, 256, 0, stream>>>(B2, Be2, D2);
    bepi_cvt<<<(D3 * 32 + 255) / 256, 256, 0, stream>>>(B3, Be3, D3);

    // layer 1: 256^2 8-phase (grid 64x8 = 512 blocks)
    tw_kernel<true><<<Bsz / 64, 256, 0, stream>>>(x, xb, Ac1, salpha, dom, 0, D0, TWb);
    gemm_lora8<<<(Bsz / 256) * (D1 / 256), 512, 0, stream>>>(xb, W1b, b1, TWb, Be1, h1b, D1, D0, D1 / 256);
    // layer 2: 256^2 8-phase (grid 64x4 = 256 blocks)
    tw_kernel<false><<<Bsz / 64, 256, 0, stream>>>(h1b, nullptr, Ac2, salpha, dom, 1, D1, TWb);
    gemm_lora8<<<(Bsz / 256) * (D2 / 256), 512, 0, stream>>>(h1b, W2b, b2, TWb, Be2, h2b, D2, D1, D2 / 256);
    // layer 3 (f32 out, old 128^2 kernel: grid 4x128)
    tw_kernel<false><<<Bsz / 64, 256, 0, stream>>>(h2b, nullptr, Ac3, salpha, dom, 2, D2, TWb);
    gemm_lora<true><<<dim3(D3 / BN, Bsz / BM), 256, 0, stream>>>(h2b, W3b, b3, TWb, Be3, d_out, D3, D2);
}

// Round 6
// 416.472 us; speedup vs baseline: 1.2458x; 1.0045x over previous
//
#include <hip/hip_runtime.h>

typedef __bf16 bf16_t;
typedef __bf16 bf16x8 __attribute__((ext_vector_type(8)));
typedef __bf16 bf16x4_v __attribute__((ext_vector_type(4)));
typedef float f32x4 __attribute__((ext_vector_type(4)));

#define AS1 __attribute__((address_space(1)))
#define AS3 __attribute__((address_space(3)))

__device__ __forceinline__ void gload_lds16(const void* g, void* l) {
    __builtin_amdgcn_global_load_lds((AS1 void*)(void*)g, (AS3 void*)l, 16, 0, 0);
}

// ---------------- routing: salpha[m][l][e] = zeta_agg[m][l] * alpha_agg[m][l][e]
__global__ void routing_kernel(
    const float* __restrict__ dom_emb, const float* __restrict__ layer_pos,
    const float* __restrict__ Wi1, const float* __restrict__ bi1,
    const float* __restrict__ Wi2, const float* __restrict__ bi2,
    const float* __restrict__ Wa1, const float* __restrict__ ba1,
    const float* __restrict__ Wa2, const float* __restrict__ ba2,
    const float* __restrict__ gate_logits, const float* __restrict__ R_benefit,
    float* __restrict__ salpha)
{
    constexpr int M = 8, L = 3, E = 4, H = 64;
    __shared__ float zl[M * L];
    __shared__ float al[M * L][E];
    __shared__ float zeta_all[M][L];
    __shared__ float alpha_all[M][L][E];
    const int t = threadIdx.x;
    const int ml = t >> 3, js = t & 7;
    if (ml < M * L) {
        const int m = ml / L, l = ml % L;
        float zacc = 0.f;
        float aacc[E] = {0.f, 0.f, 0.f, 0.f};
        for (int jj = 0; jj < 8; ++jj) {
            const int j = js * 8 + jj;
            float hz = bi1[j], ha = ba1[j];
            for (int i = 0; i < H; ++i) {
                const float de = dom_emb[m * H + i];
                const float lp = layer_pos[l * H + i];
                hz += de * Wi1[j * 2 * H + i] + lp * Wi1[j * 2 * H + H + i];
                ha += de * Wa1[j * 2 * H + i] + lp * Wa1[j * 2 * H + H + i];
            }
            hz = fmaxf(hz, 0.f); ha = fmaxf(ha, 0.f);
            zacc += hz * Wi2[j];
            for (int e = 0; e < E; ++e) aacc[e] += ha * Wa2[e * H + j];
        }
        #pragma unroll
        for (int off = 4; off >= 1; off >>= 1) {
            zacc += __shfl_down(zacc, off, 8);
            for (int e = 0; e < E; ++e) aacc[e] += __shfl_down(aacc[e], off, 8);
        }
        if (js == 0) {
            zl[ml] = zacc + bi2[0];
            for (int e = 0; e < E; ++e) al[ml][e] = aacc[e] + ba2[e];
        }
    }
    __syncthreads();
    if (t < M) {
        const int m = t;
        float v[3] = { zl[m * L + 0], zl[m * L + 1], zl[m * L + 2] };
        int di = 0; float dv = v[0];
        for (int i = 1; i < 3; ++i) if (v[i] <= dv) { dv = v[i]; di = i; }
        float mx = -1e30f;
        for (int i = 0; i < 3; ++i) if (i != di) mx = fmaxf(mx, v[i]);
        float s = 0.f, ev[3];
        for (int i = 0; i < 3; ++i) { ev[i] = (i == di) ? 0.f : expf(v[i] - mx); s += ev[i]; }
        for (int i = 0; i < 3; ++i) zeta_all[m][i] = ev[i] / s;
        for (int l = 0; l < L; ++l) {
            float a[4];
            for (int e = 0; e < 4; ++e) a[e] = al[m * L + l][e];
            int i1 = 0;
            for (int e = 1; e < 4; ++e) if (a[e] > a[i1]) i1 = e;
            int i2 = -1;
            for (int e = 0; e < 4; ++e) { if (e == i1) continue; if (i2 < 0 || a[e] > a[i2]) i2 = e; }
            const float mx2 = fmaxf(a[i1], a[i2]);
            const float e1 = expf(a[i1] - mx2), e2 = expf(a[i2] - mx2);
            const float ss = e1 + e2;
            for (int e = 0; e < 4; ++e) alpha_all[m][l][e] = 0.f;
            alpha_all[m][l][i1] = e1 / ss;
            alpha_all[m][l][i2] = e2 / ss;
        }
    }
    __syncthreads();
    if (t < M) {
        const int m = t;
        float Rrow[8]; float rs = 0.f;
        for (int n = 0; n < M; ++n) {
            const float g = gate_logits[m * M + n];
            const float rr = log1pf(expf(g)) * R_benefit[m * M + n];
            Rrow[n] = rr; rs += rr;
        }
        rs = fmaxf(rs, 1e-12f);
        for (int l = 0; l < L; ++l) {
            float zag = 0.f, aag[4] = {0.f, 0.f, 0.f, 0.f};
            for (int n = 0; n < M; ++n) {
                const float w = Rrow[n] / rs;
                zag += w * zeta_all[n][l];
                for (int e = 0; e < 4; ++e) aag[e] += w * alpha_all[n][l][e];
            }
            for (int e = 0; e < 4; ++e) salpha[(m * L + l) * 4 + e] = zag * aag[e];
        }
    }
}

// ---------------- fused f32->bf16 convert: W1,W2,W3,A1,A2,A3 into contiguous dst
__global__ void cvt_fused(const float* __restrict__ s0, const float* __restrict__ s1,
                          const float* __restrict__ s2, const float* __restrict__ s3,
                          const float* __restrict__ s4, const float* __restrict__ s5,
                          bf16_t* __restrict__ dst)
{
    const int i = blockIdx.x * 256 + threadIdx.x;   // float4 index
    constexpr int b0 = 1048576;            // W1: 2048*2048/4
    constexpr int b1 = b0 + 524288;        // W2: 1024*2048/4
    constexpr int b2 = b1 + 131072;        // W3: 512*1024/4
    constexpr int b3 = b2 + 16384;         // A1: 32*2048/4
    constexpr int b4 = b3 + 16384;         // A2: 32*2048/4
    constexpr int b5 = b4 + 8192;          // A3: 32*1024/4
    if (i >= b5) return;
    const float* src; int rel;
    if (i < b0)      { src = s0; rel = i; }
    else if (i < b1) { src = s1; rel = i - b0; }
    else if (i < b2) { src = s2; rel = i - b1; }
    else if (i < b3) { src = s3; rel = i - b2; }
    else if (i < b4) { src = s4; rel = i - b3; }
    else             { src = s5; rel = i - b4; }
    const float4 v = ((const float4*)src)[rel];
    bf16x4_v o;
    o[0] = (__bf16)v.x; o[1] = (__bf16)v.y; o[2] = (__bf16)v.z; o[3] = (__bf16)v.w;
    ((bf16x4_v*)dst)[i] = o;
}

// ---------------- fused Bepi pack: B [E][Dout][r] f32 -> [Dout][32] bf16, c=e*8+r
__global__ void bepi_fused(const float* __restrict__ B1, const float* __restrict__ B2,
                           const float* __restrict__ B3, bf16_t* __restrict__ dst)
{
    const int idx = blockIdx.x * 256 + threadIdx.x;
    constexpr int c1 = 2048 * 32, c2 = c1 + 1024 * 32, c3 = c2 + 512 * 32;
    if (idx >= c3) return;
    const float* B; int rel, Dout;
    if (idx < c1)      { B = B1; rel = idx;      Dout = 2048; }
    else if (idx < c2) { B = B2; rel = idx - c1; Dout = 1024; }
    else               { B = B3; rel = idx - c2; Dout = 512; }
    const int o = rel >> 5, c = rel & 31, e = c >> 3, r = c & 7;
    dst[idx] = (__bf16)B[((size_t)e * Dout + o) * 8 + r];
}

// ---------------- TW[b][c] = (sum_k h[b][k]*Acat[c][k]) * salpha[dom[b]][layer][c>>3]
template<bool F32IN>
__global__ void __launch_bounds__(256) tw_kernel(
    const void* __restrict__ hin, bf16_t* __restrict__ xb_out,
    const bf16_t* __restrict__ Acat, const float* __restrict__ salpha,
    const int* __restrict__ dom, const int layer, const int K,
    bf16_t* __restrict__ TWb)
{
    const int t = threadIdx.x, wid = t >> 6, lane = t & 63;
    const int rb = blockIdx.x * 64 + wid * 16;
    const int ln15 = lane & 15, kg = (lane >> 4) * 8;
    const int row = rb + ln15;
    f32x4 acc0 = {0.f, 0.f, 0.f, 0.f}, acc1 = {0.f, 0.f, 0.f, 0.f};
    const bf16_t* pa0 = Acat + (size_t)ln15 * K + kg;
    const bf16_t* pa1 = pa0 + (size_t)16 * K;
    for (int k0 = 0; k0 < K; k0 += 32) {
        bf16x8 a;
        if constexpr (F32IN) {
            const float* px = (const float*)hin + (size_t)row * K + k0 + kg;
            const float4 x0 = *(const float4*)px;
            const float4 x1 = *(const float4*)(px + 4);
            a[0] = (__bf16)x0.x; a[1] = (__bf16)x0.y; a[2] = (__bf16)x0.z; a[3] = (__bf16)x0.w;
            a[4] = (__bf16)x1.x; a[5] = (__bf16)x1.y; a[6] = (__bf16)x1.z; a[7] = (__bf16)x1.w;
            *(bf16x8*)(xb_out + (size_t)row * K + k0 + kg) = a;
        } else {
            a = *(const bf16x8*)((const bf16_t*)hin + (size_t)row * K + k0 + kg);
        }
        const bf16x8 b0 = *(const bf16x8*)(pa0 + k0);
        const bf16x8 b1 = *(const bf16x8*)(pa1 + k0);
        acc0 = __builtin_amdgcn_mfma_f32_16x16x32_bf16(a, b0, acc0, 0, 0, 0);
        acc1 = __builtin_amdgcn_mfma_f32_16x16x32_bf16(a, b1, acc1, 0, 0, 0);
    }
    const int rbase = rb + (lane >> 4) * 4;
    #pragma unroll
    for (int i = 0; i < 4; ++i) {
        const int r2 = rbase + i;
        const int d = dom[r2];
        const float* sa = salpha + (d * 3 + layer) * 4;
        const float s0 = sa[ln15 >> 3];
        const float s1 = sa[2 + (ln15 >> 3)];
        TWb[(size_t)r2 * 32 + ln15]      = (__bf16)(acc0[i] * s0);
        TWb[(size_t)r2 * 32 + 16 + ln15] = (__bf16)(acc1[i] * s1);
    }
}

// ================= 256x256 8-phase GEMM + fused LoRA K-step =================
// LDS chunk = 16KB = [kh:2][row:128][32 k] bf16, 64B rows; swizzle: 16B-slot
// bit1 ^= row bit3 (R5: conflict-free, SQ_LDS_BANK_CONFLICT=0).
// R6 schedule: plane-granular staging, uniform 2 gloads/phase:
//   P1 -> T+1.{A0,A1}.k0   P2 -> T+1.{B0,B1}.k0
//   P3 -> T+1.{A0,A1}.k1   P4 -> T+1.{B0,B1}.k1
// Waits: vmcnt(4) at P2 (covers T.k1 planes, read at P3/P4) and at P4 (covers
// T+1.k0 planes, read at T+1.P1/P2). Prologue: 8 plane loads + vmcnt(4)+barrier.
// Tail (T=NT-1, no stages): vmcnt(0) at P2, none at P4.
// Race ledger: stage targets are parity-q planes last read in tile T-1
// (k0 planes complete at T-1.P2 ENDBAR, k1 at T-1.P4 ENDBAR) -- all precede
// their stage-issue points. In-flight depth 4-8 loads, never drained to 0
// in steady state. Reads issue BEFORE stages each phase (m201 order).

__device__ __forceinline__ void stage_chunk32(const bf16_t* g, char* chunk, int t) {
    const int row = t >> 2;
    const int sl = t & 3;
    const int src = sl ^ (((row >> 3) & 1) << 1);
    gload_lds16(g + (size_t)row * 32 + src * 8, chunk + t * 16);
}

__global__ void __launch_bounds__(512, 2) gemm_lora8(
    const bf16_t* __restrict__ Abuf, const bf16_t* __restrict__ Wbuf,
    const float* __restrict__ bias, const bf16_t* __restrict__ TWb,
    const bf16_t* __restrict__ Bepi, bf16_t* __restrict__ outp,
    const int N, const int K, const int nwg_n)
{
    __shared__ __align__(1024) char lds[131072];
    const int t = threadIdx.x;
    const int wid = t >> 6, lane = t & 63;
    const int wm = wid >> 2, wn = wid & 3, wnh = wn >> 1;
    // T1: bijective XCD swizzle (grid % 8 == 0)
    const int cpx = gridDim.x >> 3;
    const int wg = (blockIdx.x & 7) * cpx + (blockIdx.x >> 3);
    const int row0 = (wg / nwg_n) * 256, col0 = (wg % nwg_n) * 256;

    const int r15 = lane & 15;
    const int swb = ((lane >> 4) ^ (((lane >> 3) & 1) << 1)) << 4;

    auto achunk = [&](int p, int c) -> char* { return lds + (((p << 1) + c) << 14); };
    auto bchunk = [&](int p, int c) -> char* { return lds + 65536 + (((p << 1) + c) << 14); };

    // hoisted staging addresses: per-thread source ptrs (advance += 64/tile)
    const int srow = t >> 2, ssl = t & 3;
    const int ssrc = ssl ^ (((srow >> 3) & 1) << 1);
    const bf16_t* sA = Abuf + (size_t)(row0 + srow) * K + ssrc * 8;
    const bf16_t* sB = Wbuf + (size_t)(col0 + srow) * K + ssrc * 8;
    const size_t halfA = (size_t)128 * K;
    const int dt16 = t * 16;

    f32x4 acc[8][4] = {};
    bf16x8 aF[4], bF[4];

    auto readA = [&](char* c, int mbase, int kq) {
        #pragma unroll
        for (int i = 0; i < 4; ++i)
            aF[i] = *(const bf16x8*)(c + (kq << 13) + (((mbase + i) * 16 + r15) << 6) + swb);
    };
    auto readB = [&](char* c, int kq) {
        #pragma unroll
        for (int nf = 0; nf < 4; ++nf)
            bF[nf] = *(const bf16x8*)(c + (kq << 13) + (((wn & 1) * 64 + nf * 16 + r15) << 6) + swb);
    };
    auto mfma16 = [&](int mbase) {
        __builtin_amdgcn_s_setprio(1);
        #pragma unroll
        for (int mf = 0; mf < 4; ++mf)
            #pragma unroll
            for (int nf = 0; nf < 4; ++nf)
                acc[mbase + mf][nf] =
                    __builtin_amdgcn_mfma_f32_16x16x32_bf16(aF[mf], bF[nf], acc[mbase + mf][nf], 0, 0, 0);
        __builtin_amdgcn_s_setprio(0);
    };
    #define MIDSYNC() do { __builtin_amdgcn_s_barrier(); \
        asm volatile("s_waitcnt lgkmcnt(0)" ::: "memory"); \
        __builtin_amdgcn_sched_barrier(0); } while (0)
    #define ENDBAR() __builtin_amdgcn_s_barrier()

    const int NT = K >> 6;  // K-tiles of 64 (NT >= 2)

    // Prologue: T0 planes in chain order {A.k0, B.k0, A.k1, B.k1}
    gload_lds16(sA,              lds + 0     + dt16);   // A0.k0
    gload_lds16(sA + halfA,      lds + 16384 + dt16);   // A1.k0
    gload_lds16(sB,              lds + 65536 + dt16);   // B0.k0
    gload_lds16(sB + halfA,      lds + 81920 + dt16);   // B1.k0
    gload_lds16(sA + 32,         lds + 8192  + dt16);   // A0.k1
    gload_lds16(sA + halfA + 32, lds + 24576 + dt16);   // A1.k1
    gload_lds16(sB + 32,         lds + 73728 + dt16);   // B0.k1
    gload_lds16(sB + halfA + 32, lds + 90112 + dt16);   // B1.k1
    asm volatile("s_waitcnt vmcnt(4)" ::: "memory");
    __builtin_amdgcn_s_barrier();

    const bf16_t* pA = sA + 64;   // stage source for tile T+1
    const bf16_t* pB = sB + 64;

    for (int T = 0; T < NT; ++T) {
        const int p = T & 1, q = p ^ 1;
        char* myA = achunk(p, wm);
        char* myB = bchunk(p, wnh);
        char* dA = lds + (q << 15) + dt16;           // achunk(q,0) dest
        char* dB = lds + 65536 + (q << 15) + dt16;   // bchunk(q,0) dest
        const bool more = (T < NT - 1);
        // P1: (mf0-3, kq0); stage T+1.A.k0
        readA(myA, 0, 0);
        readB(myB, 0);
        if (more) { gload_lds16(pA, dA); gload_lds16(pA + halfA, dA + 16384); }
        MIDSYNC();
        mfma16(0);
        ENDBAR();
        // P2: (mf4-7, kq0, bF reused); stage T+1.B.k0; wait covers T.k1 planes
        readA(myA, 4, 0);
        if (more) {
            gload_lds16(pB, dB); gload_lds16(pB + halfA, dB + 16384);
            asm volatile("s_waitcnt vmcnt(4)" ::: "memory");
        } else {
            asm volatile("s_waitcnt vmcnt(0)" ::: "memory");
        }
        MIDSYNC();
        mfma16(4);
        ENDBAR();
        // P3: (mf4-7, kq1); stage T+1.A.k1
        readA(myA, 4, 1);
        readB(myB, 1);
        if (more) { gload_lds16(pA + 32, dA + 8192); gload_lds16(pA + halfA + 32, dA + 24576); }
        MIDSYNC();
        mfma16(4);
        ENDBAR();
        // P4: (mf0-3, kq1, bF reused); stage T+1.B.k1; wait covers T+1.k0 planes
        readA(myA, 0, 1);
        if (more) {
            gload_lds16(pB + 32, dB + 8192); gload_lds16(pB + halfA + 32, dB + 24576);
            asm volatile("s_waitcnt vmcnt(4)" ::: "memory");
        }
        MIDSYNC();
        mfma16(0);
        ENDBAR();
        pA += 64; pB += 64;
    }

    // LoRA tail: one 32-wide K-step from TW [rows][32] / Bepi [cols][32].
    {
        const int q2 = NT & 1;
        stage_chunk32(TWb + (size_t)row0 * 32,          achunk(q2, 0), t);
        stage_chunk32(TWb + (size_t)(row0 + 128) * 32,  achunk(q2, 1), t);
        stage_chunk32(Bepi + (size_t)col0 * 32,         bchunk(q2, 0), t);
        stage_chunk32(Bepi + (size_t)(col0 + 128) * 32, bchunk(q2, 1), t);
        asm volatile("s_waitcnt vmcnt(0)" ::: "memory");
        __builtin_amdgcn_s_barrier();
        char* lA_ = achunk(q2, wm);
        char* lB_ = bchunk(q2, wnh);
        #pragma unroll
        for (int nf = 0; nf < 4; ++nf)
            bF[nf] = *(const bf16x8*)(lB_ + (((wn & 1) * 64 + nf * 16 + r15) << 6) + swb);
        #pragma unroll
        for (int i = 0; i < 4; ++i)
            aF[i] = *(const bf16x8*)(lA_ + ((i * 16 + r15) << 6) + swb);
        asm volatile("s_waitcnt lgkmcnt(0)" ::: "memory");
        __builtin_amdgcn_sched_barrier(0);
        mfma16(0);
        #pragma unroll
        for (int i = 0; i < 4; ++i)
            aF[i] = *(const bf16x8*)(lA_ + (((i + 4) * 16 + r15) << 6) + swb);
        asm volatile("s_waitcnt lgkmcnt(0)" ::: "memory");
        __builtin_amdgcn_sched_barrier(0);
        mfma16(4);
    }

    // Epilogue: bias + relu, bf16 store
    const int orow = row0 + wm * 128 + (lane >> 4) * 4;
    const int ocol = col0 + wn * 64 + r15;
    #pragma unroll
    for (int nf = 0; nf < 4; ++nf) {
        const int col = ocol + nf * 16;
        const float bn = bias[col];
        #pragma unroll
        for (int mf = 0; mf < 8; ++mf) {
            const int rbase = orow + mf * 16;
            #pragma unroll
            for (int i = 0; i < 4; ++i) {
                const float v = fmaxf(acc[mf][nf][i] + bn, 0.f);
                outp[(size_t)(rbase + i) * N + col] = (__bf16)v;
            }
        }
    }
    #undef MIDSYNC
    #undef ENDBAR
}

// ---------------- old 128x128 GEMM (kept for layer 3: N=512)
#define BM 128
#define BN 128
#define BK 32

template<bool OUT_F32>
__global__ void __launch_bounds__(256) gemm_lora(
    const bf16_t* __restrict__ Abuf, const bf16_t* __restrict__ Wbuf,
    const float* __restrict__ bias, const bf16_t* __restrict__ TWb,
    const bf16_t* __restrict__ Bepi, void* __restrict__ outp,
    const int N, const int K)
{
    __shared__ bf16_t lA[BM * BK];
    __shared__ bf16_t lB[BN * BK];
    const int t = threadIdx.x;
    const int row0 = blockIdx.y * BM;
    const int col0 = blockIdx.x * BN;
    const int wid = t >> 6, lane = t & 63;
    const int wr = wid >> 1, wc = wid & 1;
    const int ln15 = lane & 15, kg = (lane >> 4) * 8;
    const int srow = t >> 2, sg8 = (t & 3) * 8;
    const bf16_t* gA = Abuf + (size_t)(row0 + srow) * K + sg8;
    const bf16_t* gB = Wbuf + (size_t)(col0 + srow) * K + sg8;
    bf16_t* ldA  = &lA[t * 8];
    bf16_t* ldA2 = &lA[2048 + t * 8];
    bf16_t* ldB  = &lB[t * 8];
    bf16_t* ldB2 = &lB[2048 + t * 8];
    f32x4 acc[4][4] = {};
    const int aoff = (wr * 64 + ln15) * BK + kg;
    const int boff = (wc * 64 + ln15) * BK + kg;

    auto compute_tile = [&]() {
        bf16x8 af[4], bfr[4];
        #pragma unroll
        for (int m = 0; m < 4; ++m) af[m] = *(const bf16x8*)&lA[aoff + m * 16 * BK];
        #pragma unroll
        for (int n = 0; n < 4; ++n) bfr[n] = *(const bf16x8*)&lB[boff + n * 16 * BK];
        #pragma unroll
        for (int m = 0; m < 4; ++m)
            #pragma unroll
            for (int n = 0; n < 4; ++n)
                acc[m][n] = __builtin_amdgcn_mfma_f32_16x16x32_bf16(af[m], bfr[n], acc[m][n], 0, 0, 0);
    };

    const size_t half = (size_t)64 * K;
    const int nk = K / BK;
    for (int kt = 0; kt < nk; ++kt) {
        gload_lds16(gA + kt * BK, ldA);
        gload_lds16(gA + half + kt * BK, ldA2);
        gload_lds16(gB + kt * BK, ldB);
        gload_lds16(gB + half + kt * BK, ldB2);
        __syncthreads();
        compute_tile();
        __syncthreads();
    }
    gload_lds16(TWb + (size_t)(row0 + srow) * 32 + sg8, ldA);
    gload_lds16(TWb + (size_t)(row0 + 64 + srow) * 32 + sg8, ldA2);
    gload_lds16(Bepi + (size_t)(col0 + srow) * 32 + sg8, ldB);
    gload_lds16(Bepi + (size_t)(col0 + 64 + srow) * 32 + sg8, ldB2);
    __syncthreads();
    compute_tile();

    const int orow = row0 + wr * 64 + (lane >> 4) * 4;
    const int ocol = col0 + wc * 64 + ln15;
    #pragma unroll
    for (int n = 0; n < 4; ++n) {
        const int col = ocol + n * 16;
        const float bn = bias[col];
        #pragma unroll
        for (int m = 0; m < 4; ++m) {
            const int rbase = orow + m * 16;
            #pragma unroll
            for (int i = 0; i < 4; ++i) {
                const float v = fmaxf(acc[m][n][i] + bn, 0.f);
                if constexpr (OUT_F32)
                    ((float*)outp)[(size_t)(rbase + i) * N + col] = v;
                else
                    ((bf16_t*)outp)[(size_t)(rbase + i) * N + col] = (__bf16)v;
            }
        }
    }
}

extern "C" void kernel_launch(void* const* d_in, const int* in_sizes, int n_in,
                              void* d_out, int out_size, void* d_ws, size_t ws_size,
                              hipStream_t stream)
{
    const float* x    = (const float*)d_in[0];
    const int*   dom  = (const int*)d_in[1];
    const float* W1   = (const float*)d_in[2];  const float* b1  = (const float*)d_in[3];
    const float* W2   = (const float*)d_in[4];  const float* b2  = (const float*)d_in[5];
    const float* W3   = (const float*)d_in[6];  const float* b3  = (const float*)d_in[7];
    const float* A1   = (const float*)d_in[8];  const float* B1  = (const float*)d_in[9];
    const float* A2   = (const float*)d_in[10]; const float* B2  = (const float*)d_in[11];
    const float* A3   = (const float*)d_in[12]; const float* B3  = (const float*)d_in[13];
    const float* dome = (const float*)d_in[14]; const float* lpos = (const float*)d_in[15];
    const float* Wi1  = (const float*)d_in[16]; const float* bi1 = (const float*)d_in[17];
    const float* Wi2  = (const float*)d_in[18]; const float* bi2 = (const float*)d_in[19];
    const float* Wa1  = (const float*)d_in[20]; const float* ba1 = (const float*)d_in[21];
    const float* Wa2  = (const float*)d_in[22]; const float* ba2 = (const float*)d_in[23];
    const float* gate = (const float*)d_in[24]; const float* Rb  = (const float*)d_in[25];
    (void)in_sizes; (void)n_in; (void)out_size; (void)ws_size;

    constexpr int Bsz = 16384, D0 = 2048, D1 = 2048, D2 = 1024, D3 = 512;

    char* ws = (char*)d_ws;
    size_t off = 0;
    auto alloc = [&](size_t bytes) -> void* {
        void* p = ws + off;
        off = (off + bytes + 255) & ~(size_t)255;
        return p;
    };
    float*  salpha = (float*) alloc(8 * 3 * 4 * sizeof(float));
    // NOTE: W1b..Ac3 and Be1..Be3 are contiguous (all sizes multiples of 256B)
    // -- cvt_fused / bepi_fused rely on this.
    bf16_t* W1b = (bf16_t*)alloc((size_t)D1 * D0 * 2);
    bf16_t* W2b = (bf16_t*)alloc((size_t)D2 * D1 * 2);
    bf16_t* W3b = (bf16_t*)alloc((size_t)D3 * D2 * 2);
    bf16_t* Ac1 = (bf16_t*)alloc((size_t)32 * D0 * 2);
    bf16_t* Ac2 = (bf16_t*)alloc((size_t)32 * D1 * 2);
    bf16_t* Ac3 = (bf16_t*)alloc((size_t)32 * D2 * 2);
    bf16_t* Be1 = (bf16_t*)alloc((size_t)D1 * 32 * 2);
    bf16_t* Be2 = (bf16_t*)alloc((size_t)D2 * 32 * 2);
    bf16_t* Be3 = (bf16_t*)alloc((size_t)D3 * 32 * 2);
    bf16_t* TWb = (bf16_t*)alloc((size_t)Bsz * 32 * 2);
    bf16_t* xb  = (bf16_t*)alloc((size_t)Bsz * D0 * 2);
    bf16_t* h1b = (bf16_t*)alloc((size_t)Bsz * D1 * 2);
    bf16_t* h2b = xb;  // xb dead after layer-1 GEMM

    routing_kernel<<<1, 256, 0, stream>>>(dome, lpos, Wi1, bi1, Wi2, bi2,
                                          Wa1, ba1, Wa2, ba2, gate, Rb, salpha);

    cvt_fused<<<6816, 256, 0, stream>>>(W1, W2, W3, A1, A2, A3, W1b);
    bepi_fused<<<448, 256, 0, stream>>>(B1, B2, B3, Be1);

    // layer 1: 256^2 8-phase (grid 64x8 = 512 blocks)
    tw_kernel<true><<<Bsz / 64, 256, 0, stream>>>(x, xb, Ac1, salpha, dom, 0, D0, TWb);
    gemm_lora8<<<(Bsz / 256) * (D1 / 256), 512, 0, stream>>>(xb, W1b, b1, TWb, Be1, h1b, D1, D0, D1 / 256);
    // layer 2: 256^2 8-phase (grid 64x4 = 256 blocks)
    tw_kernel<false><<<Bsz / 64, 256, 0, stream>>>(h1b, nullptr, Ac2, salpha, dom, 1, D1, TWb);
    gemm_lora8<<<(Bsz / 256) * (D2 / 256), 512, 0, stream>>>(h1b, W2b, b2, TWb, Be2, h2b, D2, D1, D2 / 256);
    // layer 3 (f32 out, old 128^2 kernel: grid 4x128)
    tw_kernel<false><<<Bsz / 64, 256, 0, stream>>>(h2b, nullptr, Ac3, salpha, dom, 2, D2, TWb);
    gemm_lora<true><<<dim3(D3 / BN, Bsz / BM), 256, 0, stream>>>(h2b, W3b, b3, TWb, Be3, d_out, D3, D2);
}

// Round 7
// 412.440 us; speedup vs baseline: 1.2579x; 1.0098x over previous
//
#include <hip/hip_runtime.h>

typedef __bf16 bf16_t;
typedef __bf16 bf16x8 __attribute__((ext_vector_type(8)));
typedef __bf16 bf16x4_v __attribute__((ext_vector_type(4)));
typedef float f32x4 __attribute__((ext_vector_type(4)));

#define AS1 __attribute__((address_space(1)))
#define AS3 __attribute__((address_space(3)))

__device__ __forceinline__ void gload_lds16(const void* g, void* l) {
    __builtin_amdgcn_global_load_lds((AS1 void*)(void*)g, (AS3 void*)l, 16, 0, 0);
}

// ---------------- routing: salpha[m][l][e] = zeta_agg[m][l] * alpha_agg[m][l][e]
__global__ void routing_kernel(
    const float* __restrict__ dom_emb, const float* __restrict__ layer_pos,
    const float* __restrict__ Wi1, const float* __restrict__ bi1,
    const float* __restrict__ Wi2, const float* __restrict__ bi2,
    const float* __restrict__ Wa1, const float* __restrict__ ba1,
    const float* __restrict__ Wa2, const float* __restrict__ ba2,
    const float* __restrict__ gate_logits, const float* __restrict__ R_benefit,
    float* __restrict__ salpha)
{
    constexpr int M = 8, L = 3, E = 4, H = 64;
    __shared__ float zl[M * L];
    __shared__ float al[M * L][E];
    __shared__ float zeta_all[M][L];
    __shared__ float alpha_all[M][L][E];
    const int t = threadIdx.x;
    const int ml = t >> 3, js = t & 7;
    if (ml < M * L) {
        const int m = ml / L, l = ml % L;
        float zacc = 0.f;
        float aacc[E] = {0.f, 0.f, 0.f, 0.f};
        for (int jj = 0; jj < 8; ++jj) {
            const int j = js * 8 + jj;
            float hz = bi1[j], ha = ba1[j];
            for (int i = 0; i < H; ++i) {
                const float de = dom_emb[m * H + i];
                const float lp = layer_pos[l * H + i];
                hz += de * Wi1[j * 2 * H + i] + lp * Wi1[j * 2 * H + H + i];
                ha += de * Wa1[j * 2 * H + i] + lp * Wa1[j * 2 * H + H + i];
            }
            hz = fmaxf(hz, 0.f); ha = fmaxf(ha, 0.f);
            zacc += hz * Wi2[j];
            for (int e = 0; e < E; ++e) aacc[e] += ha * Wa2[e * H + j];
        }
        #pragma unroll
        for (int off = 4; off >= 1; off >>= 1) {
            zacc += __shfl_down(zacc, off, 8);
            for (int e = 0; e < E; ++e) aacc[e] += __shfl_down(aacc[e], off, 8);
        }
        if (js == 0) {
            zl[ml] = zacc + bi2[0];
            for (int e = 0; e < E; ++e) al[ml][e] = aacc[e] + ba2[e];
        }
    }
    __syncthreads();
    if (t < M) {
        const int m = t;
        float v[3] = { zl[m * L + 0], zl[m * L + 1], zl[m * L + 2] };
        int di = 0; float dv = v[0];
        for (int i = 1; i < 3; ++i) if (v[i] <= dv) { dv = v[i]; di = i; }
        float mx = -1e30f;
        for (int i = 0; i < 3; ++i) if (i != di) mx = fmaxf(mx, v[i]);
        float s = 0.f, ev[3];
        for (int i = 0; i < 3; ++i) { ev[i] = (i == di) ? 0.f : expf(v[i] - mx); s += ev[i]; }
        for (int i = 0; i < 3; ++i) zeta_all[m][i] = ev[i] / s;
        for (int l = 0; l < L; ++l) {
            float a[4];
            for (int e = 0; e < 4; ++e) a[e] = al[m * L + l][e];
            int i1 = 0;
            for (int e = 1; e < 4; ++e) if (a[e] > a[i1]) i1 = e;
            int i2 = -1;
            for (int e = 0; e < 4; ++e) { if (e == i1) continue; if (i2 < 0 || a[e] > a[i2]) i2 = e; }
            const float mx2 = fmaxf(a[i1], a[i2]);
            const float e1 = expf(a[i1] - mx2), e2 = expf(a[i2] - mx2);
            const float ss = e1 + e2;
            for (int e = 0; e < 4; ++e) alpha_all[m][l][e] = 0.f;
            alpha_all[m][l][i1] = e1 / ss;
            alpha_all[m][l][i2] = e2 / ss;
        }
    }
    __syncthreads();
    if (t < M) {
        const int m = t;
        float Rrow[8]; float rs = 0.f;
        for (int n = 0; n < M; ++n) {
            const float g = gate_logits[m * M + n];
            const float rr = log1pf(expf(g)) * R_benefit[m * M + n];
            Rrow[n] = rr; rs += rr;
        }
        rs = fmaxf(rs, 1e-12f);
        for (int l = 0; l < L; ++l) {
            float zag = 0.f, aag[4] = {0.f, 0.f, 0.f, 0.f};
            for (int n = 0; n < M; ++n) {
                const float w = Rrow[n] / rs;
                zag += w * zeta_all[n][l];
                for (int e = 0; e < 4; ++e) aag[e] += w * alpha_all[n][l][e];
            }
            for (int e = 0; e < 4; ++e) salpha[(m * L + l) * 4 + e] = zag * aag[e];
        }
    }
}

// ---------------- fused f32->bf16 convert: W1,W2,W3,A1,A2,A3 into contiguous dst
__global__ void cvt_fused(const float* __restrict__ s0, const float* __restrict__ s1,
                          const float* __restrict__ s2, const float* __restrict__ s3,
                          const float* __restrict__ s4, const float* __restrict__ s5,
                          bf16_t* __restrict__ dst)
{
    const int i = blockIdx.x * 256 + threadIdx.x;   // float4 index
    constexpr int b0 = 1048576;            // W1: 2048*2048/4
    constexpr int b1 = b0 + 524288;        // W2: 1024*2048/4
    constexpr int b2 = b1 + 131072;        // W3: 512*1024/4
    constexpr int b3 = b2 + 16384;         // A1: 32*2048/4
    constexpr int b4 = b3 + 16384;         // A2: 32*2048/4
    constexpr int b5 = b4 + 8192;          // A3: 32*1024/4
    if (i >= b5) return;
    const float* src; int rel;
    if (i < b0)      { src = s0; rel = i; }
    else if (i < b1) { src = s1; rel = i - b0; }
    else if (i < b2) { src = s2; rel = i - b1; }
    else if (i < b3) { src = s3; rel = i - b2; }
    else if (i < b4) { src = s4; rel = i - b3; }
    else             { src = s5; rel = i - b4; }
    const float4 v = ((const float4*)src)[rel];
    bf16x4_v o;
    o[0] = (__bf16)v.x; o[1] = (__bf16)v.y; o[2] = (__bf16)v.z; o[3] = (__bf16)v.w;
    ((bf16x4_v*)dst)[i] = o;
}

// ---------------- fused Bepi pack: B [E][Dout][r] f32 -> [Dout][32] bf16, c=e*8+r
__global__ void bepi_fused(const float* __restrict__ B1, const float* __restrict__ B2,
                           const float* __restrict__ B3, bf16_t* __restrict__ dst)
{
    const int idx = blockIdx.x * 256 + threadIdx.x;
    constexpr int c1 = 2048 * 32, c2 = c1 + 1024 * 32, c3 = c2 + 512 * 32;
    if (idx >= c3) return;
    const float* B; int rel, Dout;
    if (idx < c1)      { B = B1; rel = idx;      Dout = 2048; }
    else if (idx < c2) { B = B2; rel = idx - c1; Dout = 1024; }
    else               { B = B3; rel = idx - c2; Dout = 512; }
    const int o = rel >> 5, c = rel & 31, e = c >> 3, r = c & 7;
    dst[idx] = (__bf16)B[((size_t)e * Dout + o) * 8 + r];
}

// ---------------- TW[b][c] = (sum_k h[b][k]*Acat[c][k]) * salpha[dom[b]][layer][c>>3]
template<bool F32IN>
__global__ void __launch_bounds__(256) tw_kernel(
    const void* __restrict__ hin, bf16_t* __restrict__ xb_out,
    const bf16_t* __restrict__ Acat, const float* __restrict__ salpha,
    const int* __restrict__ dom, const int layer, const int K,
    bf16_t* __restrict__ TWb)
{
    const int t = threadIdx.x, wid = t >> 6, lane = t & 63;
    const int rb = blockIdx.x * 64 + wid * 16;
    const int ln15 = lane & 15, kg = (lane >> 4) * 8;
    const int row = rb + ln15;
    f32x4 acc0 = {0.f, 0.f, 0.f, 0.f}, acc1 = {0.f, 0.f, 0.f, 0.f};
    const bf16_t* pa0 = Acat + (size_t)ln15 * K + kg;
    const bf16_t* pa1 = pa0 + (size_t)16 * K;
    for (int k0 = 0; k0 < K; k0 += 32) {
        bf16x8 a;
        if constexpr (F32IN) {
            const float* px = (const float*)hin + (size_t)row * K + k0 + kg;
            const float4 x0 = *(const float4*)px;
            const float4 x1 = *(const float4*)(px + 4);
            a[0] = (__bf16)x0.x; a[1] = (__bf16)x0.y; a[2] = (__bf16)x0.z; a[3] = (__bf16)x0.w;
            a[4] = (__bf16)x1.x; a[5] = (__bf16)x1.y; a[6] = (__bf16)x1.z; a[7] = (__bf16)x1.w;
            *(bf16x8*)(xb_out + (size_t)row * K + k0 + kg) = a;
        } else {
            a = *(const bf16x8*)((const bf16_t*)hin + (size_t)row * K + k0 + kg);
        }
        const bf16x8 b0 = *(const bf16x8*)(pa0 + k0);
        const bf16x8 b1 = *(const bf16x8*)(pa1 + k0);
        acc0 = __builtin_amdgcn_mfma_f32_16x16x32_bf16(a, b0, acc0, 0, 0, 0);
        acc1 = __builtin_amdgcn_mfma_f32_16x16x32_bf16(a, b1, acc1, 0, 0, 0);
    }
    const int rbase = rb + (lane >> 4) * 4;
    #pragma unroll
    for (int i = 0; i < 4; ++i) {
        const int r2 = rbase + i;
        const int d = dom[r2];
        const float* sa = salpha + (d * 3 + layer) * 4;
        const float s0 = sa[ln15 >> 3];
        const float s1 = sa[2 + (ln15 >> 3)];
        TWb[(size_t)r2 * 32 + ln15]      = (__bf16)(acc0[i] * s0);
        TWb[(size_t)r2 * 32 + 16 + ln15] = (__bf16)(acc1[i] * s1);
    }
}

// ================= 256x256 8-phase GEMM + fused LoRA K-step =================
// LDS chunk = 16KB = [kh:2][row:128][32 k] bf16, 64B rows; swizzle: 16B-slot
// bit1 ^= row bit3 (R5: conflict-free, SQ_LDS_BANK_CONFLICT=0).
// Staging (R6): plane-granular, 2 gloads/phase:
//   P1 -> T+1.{A0,A1}.k0   P2 -> T+1.{B0,B1}.k0
//   P3 -> T+1.{A0,A1}.k1   P4 -> T+1.{B0,B1}.k1
// Waits: vmcnt(4) at P2 (covers T.k1 planes) and P4 (covers T+1.k0 planes).
// R7 change (m141 lesson): NO inline lgkmcnt(0) / sched_barrier(0) after the
// mid-phase s_barrier — the ds_reads are compiler-visible loads, so hipcc
// emits staggered lgkmcnt(N) between reads and MFMAs itself, overlapping the
// read-drain tail with MFMA issue. Explicit vmcnt stays (compiler cannot see
// the gload_lds -> ds_read dependency through LDS); barriers stay (cross-wave
// visibility of staged data).

__device__ __forceinline__ void stage_chunk32(const bf16_t* g, char* chunk, int t) {
    const int row = t >> 2;
    const int sl = t & 3;
    const int src = sl ^ (((row >> 3) & 1) << 1);
    gload_lds16(g + (size_t)row * 32 + src * 8, chunk + t * 16);
}

__global__ void __launch_bounds__(512, 2) gemm_lora8(
    const bf16_t* __restrict__ Abuf, const bf16_t* __restrict__ Wbuf,
    const float* __restrict__ bias, const bf16_t* __restrict__ TWb,
    const bf16_t* __restrict__ Bepi, bf16_t* __restrict__ outp,
    const int N, const int K, const int nwg_n)
{
    __shared__ __align__(1024) char lds[131072];
    const int t = threadIdx.x;
    const int wid = t >> 6, lane = t & 63;
    const int wm = wid >> 2, wn = wid & 3, wnh = wn >> 1;
    // T1: bijective XCD swizzle (grid % 8 == 0)
    const int cpx = gridDim.x >> 3;
    const int wg = (blockIdx.x & 7) * cpx + (blockIdx.x >> 3);
    const int row0 = (wg / nwg_n) * 256, col0 = (wg % nwg_n) * 256;

    const int r15 = lane & 15;
    const int swb = ((lane >> 4) ^ (((lane >> 3) & 1) << 1)) << 4;

    auto achunk = [&](int p, int c) -> char* { return lds + (((p << 1) + c) << 14); };
    auto bchunk = [&](int p, int c) -> char* { return lds + 65536 + (((p << 1) + c) << 14); };

    // hoisted staging addresses: per-thread source ptrs (advance += 64/tile)
    const int srow = t >> 2, ssl = t & 3;
    const int ssrc = ssl ^ (((srow >> 3) & 1) << 1);
    const bf16_t* sA = Abuf + (size_t)(row0 + srow) * K + ssrc * 8;
    const bf16_t* sB = Wbuf + (size_t)(col0 + srow) * K + ssrc * 8;
    const size_t halfA = (size_t)128 * K;
    const int dt16 = t * 16;

    f32x4 acc[8][4] = {};
    bf16x8 aF[4], bF[4];

    auto readA = [&](char* c, int mbase, int kq) {
        #pragma unroll
        for (int i = 0; i < 4; ++i)
            aF[i] = *(const bf16x8*)(c + (kq << 13) + (((mbase + i) * 16 + r15) << 6) + swb);
    };
    auto readB = [&](char* c, int kq) {
        #pragma unroll
        for (int nf = 0; nf < 4; ++nf)
            bF[nf] = *(const bf16x8*)(c + (kq << 13) + (((wn & 1) * 64 + nf * 16 + r15) << 6) + swb);
    };
    auto mfma16 = [&](int mbase) {
        __builtin_amdgcn_s_setprio(1);
        #pragma unroll
        for (int mf = 0; mf < 4; ++mf)
            #pragma unroll
            for (int nf = 0; nf < 4; ++nf)
                acc[mbase + mf][nf] =
                    __builtin_amdgcn_mfma_f32_16x16x32_bf16(aF[mf], bF[nf], acc[mbase + mf][nf], 0, 0, 0);
        __builtin_amdgcn_s_setprio(0);
    };
    #define BAR() __builtin_amdgcn_s_barrier()

    const int NT = K >> 6;  // K-tiles of 64 (NT >= 2)

    // Prologue: T0 planes in chain order {A.k0, B.k0, A.k1, B.k1}
    gload_lds16(sA,              lds + 0     + dt16);   // A0.k0
    gload_lds16(sA + halfA,      lds + 16384 + dt16);   // A1.k0
    gload_lds16(sB,              lds + 65536 + dt16);   // B0.k0
    gload_lds16(sB + halfA,      lds + 81920 + dt16);   // B1.k0
    gload_lds16(sA + 32,         lds + 8192  + dt16);   // A0.k1
    gload_lds16(sA + halfA + 32, lds + 24576 + dt16);   // A1.k1
    gload_lds16(sB + 32,         lds + 73728 + dt16);   // B0.k1
    gload_lds16(sB + halfA + 32, lds + 90112 + dt16);   // B1.k1
    asm volatile("s_waitcnt vmcnt(4)" ::: "memory");
    __builtin_amdgcn_s_barrier();

    const bf16_t* pA = sA + 64;   // stage source for tile T+1
    const bf16_t* pB = sB + 64;

    for (int T = 0; T < NT; ++T) {
        const int p = T & 1, q = p ^ 1;
        char* myA = achunk(p, wm);
        char* myB = bchunk(p, wnh);
        char* dA = lds + (q << 15) + dt16;           // achunk(q,0) dest
        char* dB = lds + 65536 + (q << 15) + dt16;   // bchunk(q,0) dest
        const bool more = (T < NT - 1);
        // P1: (mf0-3, kq0); stage T+1.A.k0
        readA(myA, 0, 0);
        readB(myB, 0);
        if (more) { gload_lds16(pA, dA); gload_lds16(pA + halfA, dA + 16384); }
        BAR();
        mfma16(0);
        BAR();
        // P2: (mf4-7, kq0, bF reused); stage T+1.B.k0; wait covers T.k1 planes
        readA(myA, 4, 0);
        if (more) {
            gload_lds16(pB, dB); gload_lds16(pB + halfA, dB + 16384);
            asm volatile("s_waitcnt vmcnt(4)" ::: "memory");
        } else {
            asm volatile("s_waitcnt vmcnt(0)" ::: "memory");
        }
        BAR();
        mfma16(4);
        BAR();
        // P3: (mf4-7, kq1); stage T+1.A.k1
        readA(myA, 4, 1);
        readB(myB, 1);
        if (more) { gload_lds16(pA + 32, dA + 8192); gload_lds16(pA + halfA + 32, dA + 24576); }
        BAR();
        mfma16(4);
        BAR();
        // P4: (mf0-3, kq1, bF reused); stage T+1.B.k1; wait covers T+1.k0 planes
        readA(myA, 0, 1);
        if (more) {
            gload_lds16(pB + 32, dB + 8192); gload_lds16(pB + halfA + 32, dB + 24576);
            asm volatile("s_waitcnt vmcnt(4)" ::: "memory");
        }
        BAR();
        mfma16(0);
        BAR();
        pA += 64; pB += 64;
    }

    // LoRA tail: one 32-wide K-step from TW [rows][32] / Bepi [cols][32].
    {
        const int q2 = NT & 1;
        stage_chunk32(TWb + (size_t)row0 * 32,          achunk(q2, 0), t);
        stage_chunk32(TWb + (size_t)(row0 + 128) * 32,  achunk(q2, 1), t);
        stage_chunk32(Bepi + (size_t)col0 * 32,         bchunk(q2, 0), t);
        stage_chunk32(Bepi + (size_t)(col0 + 128) * 32, bchunk(q2, 1), t);
        asm volatile("s_waitcnt vmcnt(0)" ::: "memory");
        __builtin_amdgcn_s_barrier();
        char* lA_ = achunk(q2, wm);
        char* lB_ = bchunk(q2, wnh);
        #pragma unroll
        for (int nf = 0; nf < 4; ++nf)
            bF[nf] = *(const bf16x8*)(lB_ + (((wn & 1) * 64 + nf * 16 + r15) << 6) + swb);
        #pragma unroll
        for (int i = 0; i < 4; ++i)
            aF[i] = *(const bf16x8*)(lA_ + ((i * 16 + r15) << 6) + swb);
        mfma16(0);
        #pragma unroll
        for (int i = 0; i < 4; ++i)
            aF[i] = *(const bf16x8*)(lA_ + (((i + 4) * 16 + r15) << 6) + swb);
        mfma16(4);
    }

    // Epilogue: bias + relu, bf16 store
    const int orow = row0 + wm * 128 + (lane >> 4) * 4;
    const int ocol = col0 + wn * 64 + r15;
    #pragma unroll
    for (int nf = 0; nf < 4; ++nf) {
        const int col = ocol + nf * 16;
        const float bn = bias[col];
        #pragma unroll
        for (int mf = 0; mf < 8; ++mf) {
            const int rbase = orow + mf * 16;
            #pragma unroll
            for (int i = 0; i < 4; ++i) {
                const float v = fmaxf(acc[mf][nf][i] + bn, 0.f);
                outp[(size_t)(rbase + i) * N + col] = (__bf16)v;
            }
        }
    }
    #undef BAR
}

// ---------------- old 128x128 GEMM (kept for layer 3: N=512)
#define BM 128
#define BN 128
#define BK 32

template<bool OUT_F32>
__global__ void __launch_bounds__(256) gemm_lora(
    const bf16_t* __restrict__ Abuf, const bf16_t* __restrict__ Wbuf,
    const float* __restrict__ bias, const bf16_t* __restrict__ TWb,
    const bf16_t* __restrict__ Bepi, void* __restrict__ outp,
    const int N, const int K)
{
    __shared__ bf16_t lA[BM * BK];
    __shared__ bf16_t lB[BN * BK];
    const int t = threadIdx.x;
    const int row0 = blockIdx.y * BM;
    const int col0 = blockIdx.x * BN;
    const int wid = t >> 6, lane = t & 63;
    const int wr = wid >> 1, wc = wid & 1;
    const int ln15 = lane & 15, kg = (lane >> 4) * 8;
    const int srow = t >> 2, sg8 = (t & 3) * 8;
    const bf16_t* gA = Abuf + (size_t)(row0 + srow) * K + sg8;
    const bf16_t* gB = Wbuf + (size_t)(col0 + srow) * K + sg8;
    bf16_t* ldA  = &lA[t * 8];
    bf16_t* ldA2 = &lA[2048 + t * 8];
    bf16_t* ldB  = &lB[t * 8];
    bf16_t* ldB2 = &lB[2048 + t * 8];
    f32x4 acc[4][4] = {};
    const int aoff = (wr * 64 + ln15) * BK + kg;
    const int boff = (wc * 64 + ln15) * BK + kg;

    auto compute_tile = [&]() {
        bf16x8 af[4], bfr[4];
        #pragma unroll
        for (int m = 0; m < 4; ++m) af[m] = *(const bf16x8*)&lA[aoff + m * 16 * BK];
        #pragma unroll
        for (int n = 0; n < 4; ++n) bfr[n] = *(const bf16x8*)&lB[boff + n * 16 * BK];
        #pragma unroll
        for (int m = 0; m < 4; ++m)
            #pragma unroll
            for (int n = 0; n < 4; ++n)
                acc[m][n] = __builtin_amdgcn_mfma_f32_16x16x32_bf16(af[m], bfr[n], acc[m][n], 0, 0, 0);
    };

    const size_t half = (size_t)64 * K;
    const int nk = K / BK;
    for (int kt = 0; kt < nk; ++kt) {
        gload_lds16(gA + kt * BK, ldA);
        gload_lds16(gA + half + kt * BK, ldA2);
        gload_lds16(gB + kt * BK, ldB);
        gload_lds16(gB + half + kt * BK, ldB2);
        __syncthreads();
        compute_tile();
        __syncthreads();
    }
    gload_lds16(TWb + (size_t)(row0 + srow) * 32 + sg8, ldA);
    gload_lds16(TWb + (size_t)(row0 + 64 + srow) * 32 + sg8, ldA2);
    gload_lds16(Bepi + (size_t)(col0 + srow) * 32 + sg8, ldB);
    gload_lds16(Bepi + (size_t)(col0 + 64 + srow) * 32 + sg8, ldB2);
    __syncthreads();
    compute_tile();

    const int orow = row0 + wr * 64 + (lane >> 4) * 4;
    const int ocol = col0 + wc * 64 + ln15;
    #pragma unroll
    for (int n = 0; n < 4; ++n) {
        const int col = ocol + n * 16;
        const float bn = bias[col];
        #pragma unroll
        for (int m = 0; m < 4; ++m) {
            const int rbase = orow + m * 16;
            #pragma unroll
            for (int i = 0; i < 4; ++i) {
                const float v = fmaxf(acc[m][n][i] + bn, 0.f);
                if constexpr (OUT_F32)
                    ((float*)outp)[(size_t)(rbase + i) * N + col] = v;
                else
                    ((bf16_t*)outp)[(size_t)(rbase + i) * N + col] = (__bf16)v;
            }
        }
    }
}

extern "C" void kernel_launch(void* const* d_in, const int* in_sizes, int n_in,
                              void* d_out, int out_size, void* d_ws, size_t ws_size,
                              hipStream_t stream)
{
    const float* x    = (const float*)d_in[0];
    const int*   dom  = (const int*)d_in[1];
    const float* W1   = (const float*)d_in[2];  const float* b1  = (const float*)d_in[3];
    const float* W2   = (const float*)d_in[4];  const float* b2  = (const float*)d_in[5];
    const float* W3   = (const float*)d_in[6];  const float* b3  = (const float*)d_in[7];
    const float* A1   = (const float*)d_in[8];  const float* B1  = (const float*)d_in[9];
    const float* A2   = (const float*)d_in[10]; const float* B2  = (const float*)d_in[11];
    const float* A3   = (const float*)d_in[12]; const float* B3  = (const float*)d_in[13];
    const float* dome = (const float*)d_in[14]; const float* lpos = (const float*)d_in[15];
    const float* Wi1  = (const float*)d_in[16]; const float* bi1 = (const float*)d_in[17];
    const float* Wi2  = (const float*)d_in[18]; const float* bi2 = (const float*)d_in[19];
    const float* Wa1  = (const float*)d_in[20]; const float* ba1 = (const float*)d_in[21];
    const float* Wa2  = (const float*)d_in[22]; const float* ba2 = (const float*)d_in[23];
    const float* gate = (const float*)d_in[24]; const float* Rb  = (const float*)d_in[25];
    (void)in_sizes; (void)n_in; (void)out_size; (void)ws_size;

    constexpr int Bsz = 16384, D0 = 2048, D1 = 2048, D2 = 1024, D3 = 512;

    char* ws = (char*)d_ws;
    size_t off = 0;
    auto alloc = [&](size_t bytes) -> void* {
        void* p = ws + off;
        off = (off + bytes + 255) & ~(size_t)255;
        return p;
    };
    float*  salpha = (float*) alloc(8 * 3 * 4 * sizeof(float));
    // NOTE: W1b..Ac3 and Be1..Be3 are contiguous (all sizes multiples of 256B)
    // -- cvt_fused / bepi_fused rely on this.
    bf16_t* W1b = (bf16_t*)alloc((size_t)D1 * D0 * 2);
    bf16_t* W2b = (bf16_t*)alloc((size_t)D2 * D1 * 2);
    bf16_t* W3b = (bf16_t*)alloc((size_t)D3 * D2 * 2);
    bf16_t* Ac1 = (bf16_t*)alloc((size_t)32 * D0 * 2);
    bf16_t* Ac2 = (bf16_t*)alloc((size_t)32 * D1 * 2);
    bf16_t* Ac3 = (bf16_t*)alloc((size_t)32 * D2 * 2);
    bf16_t* Be1 = (bf16_t*)alloc((size_t)D1 * 32 * 2);
    bf16_t* Be2 = (bf16_t*)alloc((size_t)D2 * 32 * 2);
    bf16_t* Be3 = (bf16_t*)alloc((size_t)D3 * 32 * 2);
    bf16_t* TWb = (bf16_t*)alloc((size_t)Bsz * 32 * 2);
    bf16_t* xb  = (bf16_t*)alloc((size_t)Bsz * D0 * 2);
    bf16_t* h1b = (bf16_t*)alloc((size_t)Bsz * D1 * 2);
    bf16_t* h2b = xb;  // xb dead after layer-1 GEMM

    routing_kernel<<<1, 256, 0, stream>>>(dome, lpos, Wi1, bi1, Wi2, bi2,
                                          Wa1, ba1, Wa2, ba2, gate, Rb, salpha);

    cvt_fused<<<6816, 256, 0, stream>>>(W1, W2, W3, A1, A2, A3, W1b);
    bepi_fused<<<448, 256, 0, stream>>>(B1, B2, B3, Be1);

    // layer 1: 256^2 8-phase (grid 64x8 = 512 blocks)
    tw_kernel<true><<<Bsz / 64, 256, 0, stream>>>(x, xb, Ac1, salpha, dom, 0, D0, TWb);
    gemm_lora8<<<(Bsz / 256) * (D1 / 256), 512, 0, stream>>>(xb, W1b, b1, TWb, Be1, h1b, D1, D0, D1 / 256);
    // layer 2: 256^2 8-phase (grid 64x4 = 256 blocks)
    tw_kernel<false><<<Bsz / 64, 256, 0, stream>>>(h1b, nullptr, Ac2, salpha, dom, 1, D1, TWb);
    gemm_lora8<<<(Bsz / 256) * (D2 / 256), 512, 0, stream>>>(h1b, W2b, b2, TWb, Be2, h2b, D2, D1, D2 / 256);
    // layer 3 (f32 out, old 128^2 kernel: grid 4x128)
    tw_kernel<false><<<Bsz / 64, 256, 0, stream>>>(h2b, nullptr, Ac3, salpha, dom, 2, D2, TWb);
    gemm_lora<true><<<dim3(D3 / BN, Bsz / BM), 256, 0, stream>>>(h2b, W3b, b3, TWb, Be3, d_out, D3, D2);
}

// Round 10
// 403.652 us; speedup vs baseline: 1.2853x; 1.0218x over previous
//
#include <hip/hip_runtime.h>

typedef __bf16 bf16_t;
typedef __bf16 bf16x8 __attribute__((ext_vector_type(8)));
typedef __bf16 bf16x4_v __attribute__((ext_vector_type(4)));
typedef float f32x4 __attribute__((ext_vector_type(4)));

#define AS1 __attribute__((address_space(1)))
#define AS3 __attribute__((address_space(3)))

__device__ __forceinline__ void gload_lds16(const void* g, void* l) {
    __builtin_amdgcn_global_load_lds((AS1 void*)(void*)g, (AS3 void*)l, 16, 0, 0);
}

// ---------------- routing: salpha[m][l][e] = zeta_agg[m][l] * alpha_agg[m][l][e]
__global__ void routing_kernel(
    const float* __restrict__ dom_emb, const float* __restrict__ layer_pos,
    const float* __restrict__ Wi1, const float* __restrict__ bi1,
    const float* __restrict__ Wi2, const float* __restrict__ bi2,
    const float* __restrict__ Wa1, const float* __restrict__ ba1,
    const float* __restrict__ Wa2, const float* __restrict__ ba2,
    const float* __restrict__ gate_logits, const float* __restrict__ R_benefit,
    float* __restrict__ salpha)
{
    constexpr int M = 8, L = 3, E = 4, H = 64;
    __shared__ float zl[M * L];
    __shared__ float al[M * L][E];
    __shared__ float zeta_all[M][L];
    __shared__ float alpha_all[M][L][E];
    const int t = threadIdx.x;
    const int ml = t >> 3, js = t & 7;
    if (ml < M * L) {
        const int m = ml / L, l = ml % L;
        float zacc = 0.f;
        float aacc[E] = {0.f, 0.f, 0.f, 0.f};
        for (int jj = 0; jj < 8; ++jj) {
            const int j = js * 8 + jj;
            float hz = bi1[j], ha = ba1[j];
            for (int i = 0; i < H; ++i) {
                const float de = dom_emb[m * H + i];
                const float lp = layer_pos[l * H + i];
                hz += de * Wi1[j * 2 * H + i] + lp * Wi1[j * 2 * H + H + i];
                ha += de * Wa1[j * 2 * H + i] + lp * Wa1[j * 2 * H + H + i];
            }
            hz = fmaxf(hz, 0.f); ha = fmaxf(ha, 0.f);
            zacc += hz * Wi2[j];
            for (int e = 0; e < E; ++e) aacc[e] += ha * Wa2[e * H + j];
        }
        #pragma unroll
        for (int off = 4; off >= 1; off >>= 1) {
            zacc += __shfl_down(zacc, off, 8);
            for (int e = 0; e < E; ++e) aacc[e] += __shfl_down(aacc[e], off, 8);
        }
        if (js == 0) {
            zl[ml] = zacc + bi2[0];
            for (int e = 0; e < E; ++e) al[ml][e] = aacc[e] + ba2[e];
        }
    }
    __syncthreads();
    if (t < M) {
        const int m = t;
        float v[3] = { zl[m * L + 0], zl[m * L + 1], zl[m * L + 2] };
        int di = 0; float dv = v[0];
        for (int i = 1; i < 3; ++i) if (v[i] <= dv) { dv = v[i]; di = i; }
        float mx = -1e30f;
        for (int i = 0; i < 3; ++i) if (i != di) mx = fmaxf(mx, v[i]);
        float s = 0.f, ev[3];
        for (int i = 0; i < 3; ++i) { ev[i] = (i == di) ? 0.f : expf(v[i] - mx); s += ev[i]; }
        for (int i = 0; i < 3; ++i) zeta_all[m][i] = ev[i] / s;
        for (int l = 0; l < L; ++l) {
            float a[4];
            for (int e = 0; e < 4; ++e) a[e] = al[m * L + l][e];
            int i1 = 0;
            for (int e = 1; e < 4; ++e) if (a[e] > a[i1]) i1 = e;
            int i2 = -1;
            for (int e = 0; e < 4; ++e) { if (e == i1) continue; if (i2 < 0 || a[e] > a[i2]) i2 = e; }
            const float mx2 = fmaxf(a[i1], a[i2]);
            const float e1 = expf(a[i1] - mx2), e2 = expf(a[i2] - mx2);
            const float ss = e1 + e2;
            for (int e = 0; e < 4; ++e) alpha_all[m][l][e] = 0.f;
            alpha_all[m][l][i1] = e1 / ss;
            alpha_all[m][l][i2] = e2 / ss;
        }
    }
    __syncthreads();
    if (t < M) {
        const int m = t;
        float Rrow[8]; float rs = 0.f;
        for (int n = 0; n < M; ++n) {
            const float g = gate_logits[m * M + n];
            const float rr = log1pf(expf(g)) * R_benefit[m * M + n];
            Rrow[n] = rr; rs += rr;
        }
        rs = fmaxf(rs, 1e-12f);
        for (int l = 0; l < L; ++l) {
            float zag = 0.f, aag[4] = {0.f, 0.f, 0.f, 0.f};
            for (int n = 0; n < M; ++n) {
                const float w = Rrow[n] / rs;
                zag += w * zeta_all[n][l];
                for (int e = 0; e < 4; ++e) aag[e] += w * alpha_all[n][l][e];
            }
            for (int e = 0; e < 4; ++e) salpha[(m * L + l) * 4 + e] = zag * aag[e];
        }
    }
}

// ---------------- fused f32->bf16 convert: W1,W2,W3,A1,A2,A3 into contiguous dst
__global__ void cvt_fused(const float* __restrict__ s0, const float* __restrict__ s1,
                          const float* __restrict__ s2, const float* __restrict__ s3,
                          const float* __restrict__ s4, const float* __restrict__ s5,
                          bf16_t* __restrict__ dst)
{
    const int i = blockIdx.x * 256 + threadIdx.x;   // float4 index
    constexpr int b0 = 1048576;
    constexpr int b1 = b0 + 524288;
    constexpr int b2 = b1 + 131072;
    constexpr int b3 = b2 + 16384;
    constexpr int b4 = b3 + 16384;
    constexpr int b5 = b4 + 8192;
    if (i >= b5) return;
    const float* src; int rel;
    if (i < b0)      { src = s0; rel = i; }
    else if (i < b1) { src = s1; rel = i - b0; }
    else if (i < b2) { src = s2; rel = i - b1; }
    else if (i < b3) { src = s3; rel = i - b2; }
    else if (i < b4) { src = s4; rel = i - b3; }
    else             { src = s5; rel = i - b4; }
    const float4 v = ((const float4*)src)[rel];
    bf16x4_v o;
    o[0] = (__bf16)v.x; o[1] = (__bf16)v.y; o[2] = (__bf16)v.z; o[3] = (__bf16)v.w;
    ((bf16x4_v*)dst)[i] = o;
}

// ---------------- fused Bepi pack: B [E][Dout][r] f32 -> [Dout][32] bf16, c=e*8+r
__global__ void bepi_fused(const float* __restrict__ B1, const float* __restrict__ B2,
                           const float* __restrict__ B3, bf16_t* __restrict__ dst)
{
    const int idx = blockIdx.x * 256 + threadIdx.x;
    constexpr int c1 = 2048 * 32, c2 = c1 + 1024 * 32, c3 = c2 + 512 * 32;
    if (idx >= c3) return;
    const float* B; int rel, Dout;
    if (idx < c1)      { B = B1; rel = idx;      Dout = 2048; }
    else if (idx < c2) { B = B2; rel = idx - c1; Dout = 1024; }
    else               { B = B3; rel = idx - c2; Dout = 512; }
    const int o = rel >> 5, c = rel & 31, e = c >> 3, r = c & 7;
    dst[idx] = (__bf16)B[((size_t)e * Dout + o) * 8 + r];
}

// ---------------- TW[b][c] = (sum_k h[b][k]*Acat[c][k]) * salpha[dom[b]][layer][c>>3]
template<bool F32IN>
__global__ void __launch_bounds__(256) tw_kernel(
    const void* __restrict__ hin, bf16_t* __restrict__ xb_out,
    const bf16_t* __restrict__ Acat, const float* __restrict__ salpha,
    const int* __restrict__ dom, const int layer, const int K,
    bf16_t* __restrict__ TWb)
{
    const int t = threadIdx.x, wid = t >> 6, lane = t & 63;
    const int rb = blockIdx.x * 64 + wid * 16;
    const int ln15 = lane & 15, kg = (lane >> 4) * 8;
    const int row = rb + ln15;
    f32x4 acc0 = {0.f, 0.f, 0.f, 0.f}, acc1 = {0.f, 0.f, 0.f, 0.f};
    const bf16_t* pa0 = Acat + (size_t)ln15 * K + kg;
    const bf16_t* pa1 = pa0 + (size_t)16 * K;
    for (int k0 = 0; k0 < K; k0 += 32) {
        bf16x8 a;
        if constexpr (F32IN) {
            const float* px = (const float*)hin + (size_t)row * K + k0 + kg;
            const float4 x0 = *(const float4*)px;
            const float4 x1 = *(const float4*)(px + 4);
            a[0] = (__bf16)x0.x; a[1] = (__bf16)x0.y; a[2] = (__bf16)x0.z; a[3] = (__bf16)x0.w;
            a[4] = (__bf16)x1.x; a[5] = (__bf16)x1.y; a[6] = (__bf16)x1.z; a[7] = (__bf16)x1.w;
            *(bf16x8*)(xb_out + (size_t)row * K + k0 + kg) = a;
        } else {
            a = *(const bf16x8*)((const bf16_t*)hin + (size_t)row * K + k0 + kg);
        }
        const bf16x8 b0 = *(const bf16x8*)(pa0 + k0);
        const bf16x8 b1 = *(const bf16x8*)(pa1 + k0);
        acc0 = __builtin_amdgcn_mfma_f32_16x16x32_bf16(a, b0, acc0, 0, 0, 0);
        acc1 = __builtin_amdgcn_mfma_f32_16x16x32_bf16(a, b1, acc1, 0, 0, 0);
    }
    const int rbase = rb + (lane >> 4) * 4;
    #pragma unroll
    for (int i = 0; i < 4; ++i) {
        const int r2 = rbase + i;
        const int d = dom[r2];
        const float* sa = salpha + (d * 3 + layer) * 4;
        const float s0 = sa[ln15 >> 3];
        const float s1 = sa[2 + (ln15 >> 3)];
        TWb[(size_t)r2 * 32 + ln15]      = (__bf16)(acc0[i] * s0);
        TWb[(size_t)r2 * 32 + 16 + ln15] = (__bf16)(acc1[i] * s1);
    }
}

// ================= 256x256 8-phase GEMM + fused LoRA K-step =================
// LDS chunk = 16KB = [kh:2][row:128][32 k] bf16, 64B rows; swizzle: 16B-slot
// bit1 ^= row bit3 (R5-verified conflict-free, SQ_LDS_BANK_CONFLICT=0).
// R10: R8/R9's correctness failure root-caused: layer-2 call passed template
// K=1024 (the OUTPUT dim) instead of K=2048 (reduction dim = D1). The kernel
// itself was correct. Template<int K> + manual 2-tile unroll retained
// (compile-time chunk bases / trip counts); epilogue = direct stores (known
// correct). Schedule/ledger unchanged from R6 (plane staging P1:A.k0 P2:B.k0
// P3:A.k1 P4:B.k1 for T+1; vmcnt(4) at P2/P4; drain at last tile's P2).

__device__ __forceinline__ void stage_chunk32(const bf16_t* g, char* chunk, int t) {
    const int row = t >> 2;
    const int sl = t & 3;
    const int src = sl ^ (((row >> 3) & 1) << 1);
    gload_lds16(g + (size_t)row * 32 + src * 8, chunk + t * 16);
}

template<int K>
__global__ void __launch_bounds__(512, 2) gemm_lora8(
    const bf16_t* __restrict__ Abuf, const bf16_t* __restrict__ Wbuf,
    const float* __restrict__ bias, const bf16_t* __restrict__ TWb,
    const bf16_t* __restrict__ Bepi, bf16_t* __restrict__ outp,
    const int N, const int nwg_n)
{
    __shared__ __align__(1024) char lds[131072];
    const int t = threadIdx.x;
    const int wid = t >> 6, lane = t & 63;
    const int wm = wid >> 2, wn = wid & 3, wnh = wn >> 1;
    const int cpx = gridDim.x >> 3;
    const int wg = (blockIdx.x & 7) * cpx + (blockIdx.x >> 3);
    const int row0 = (wg / nwg_n) * 256, col0 = (wg % nwg_n) * 256;

    const int r15 = lane & 15;
    const int swb = ((lane >> 4) ^ (((lane >> 3) & 1) << 1)) << 4;

    // compile-time-friendly chunk pointers
    char* cA0 = lds + (wm << 14);                  // achunk(0, wm)
    char* cA1 = lds + ((2 + wm) << 14);            // achunk(1, wm)
    char* cB0 = lds + 65536 + (wnh << 14);         // bchunk(0, wnh)
    char* cB1 = lds + 65536 + ((2 + wnh) << 14);   // bchunk(1, wnh)
    const int dt16 = t * 16;
    char* dA0 = lds + 32768 + dt16;                // dest achunk(1,0) (q=1 when p=0)
    char* dA1 = lds + dt16;                        // dest achunk(0,0)
    char* dB0 = lds + 65536 + 32768 + dt16;
    char* dB1 = lds + 65536 + dt16;

    // staging source ptrs (inverse-swizzled slot), advance +64/tile
    const int srow = t >> 2, ssl = t & 3;
    const int ssrc = ssl ^ (((srow >> 3) & 1) << 1);
    const bf16_t* sA = Abuf + (size_t)(row0 + srow) * K + ssrc * 8;
    const bf16_t* sB = Wbuf + (size_t)(col0 + srow) * K + ssrc * 8;
    constexpr size_t halfA = (size_t)128 * K;

    f32x4 acc[8][4] = {};
    bf16x8 aF[4], bF[4];

    auto readA = [&](char* c, int mbase, int kq) {
        #pragma unroll
        for (int i = 0; i < 4; ++i)
            aF[i] = *(const bf16x8*)(c + (kq << 13) + (((mbase + i) * 16 + r15) << 6) + swb);
    };
    auto readB = [&](char* c, int kq) {
        #pragma unroll
        for (int nf = 0; nf < 4; ++nf)
            bF[nf] = *(const bf16x8*)(c + (kq << 13) + (((wn & 1) * 64 + nf * 16 + r15) << 6) + swb);
    };
    auto mfma16 = [&](int mbase) {
        __builtin_amdgcn_s_setprio(1);
        #pragma unroll
        for (int mf = 0; mf < 4; ++mf)
            #pragma unroll
            for (int nf = 0; nf < 4; ++nf)
                acc[mbase + mf][nf] =
                    __builtin_amdgcn_mfma_f32_16x16x32_bf16(aF[mf], bF[nf], acc[mbase + mf][nf], 0, 0, 0);
        __builtin_amdgcn_s_setprio(0);
    };
    #define BAR() __builtin_amdgcn_s_barrier()

    constexpr int NT = K >> 6;   // even, >= 16

    // Prologue: T0 planes in chain order {A.k0, B.k0, A.k1, B.k1}
    gload_lds16(sA,              lds + 0     + dt16);
    gload_lds16(sA + halfA,      lds + 16384 + dt16);
    gload_lds16(sB,              lds + 65536 + dt16);
    gload_lds16(sB + halfA,      lds + 81920 + dt16);
    gload_lds16(sA + 32,         lds + 8192  + dt16);
    gload_lds16(sA + halfA + 32, lds + 24576 + dt16);
    gload_lds16(sB + 32,         lds + 73728 + dt16);
    gload_lds16(sB + halfA + 32, lds + 90112 + dt16);
    asm volatile("s_waitcnt vmcnt(4)" ::: "memory");
    __builtin_amdgcn_s_barrier();

    const bf16_t* pA = sA + 64;
    const bf16_t* pB = sB + 64;

    auto TILE = [&](const int p, const bool more) {
        char* myA = p ? cA1 : cA0;
        char* myB = p ? cB1 : cB0;
        char* dA  = p ? dA1 : dA0;
        char* dB  = p ? dB1 : dB0;
        // P1: (mf0-3, kq0); stage T+1.A.k0
        readA(myA, 0, 0);
        readB(myB, 0);
        if (more) { gload_lds16(pA, dA); gload_lds16(pA + halfA, dA + 16384); }
        BAR();
        mfma16(0);
        BAR();
        // P2: (mf4-7, kq0); stage T+1.B.k0; wait covers T.k1 planes
        readA(myA, 4, 0);
        if (more) {
            gload_lds16(pB, dB); gload_lds16(pB + halfA, dB + 16384);
            asm volatile("s_waitcnt vmcnt(4)" ::: "memory");
        } else {
            asm volatile("s_waitcnt vmcnt(0)" ::: "memory");
        }
        BAR();
        mfma16(4);
        BAR();
        // P3: (mf4-7, kq1); stage T+1.A.k1
        readA(myA, 4, 1);
        readB(myB, 1);
        if (more) { gload_lds16(pA + 32, dA + 8192); gload_lds16(pA + halfA + 32, dA + 24576); }
        BAR();
        mfma16(4);
        BAR();
        // P4: (mf0-3, kq1); stage T+1.B.k1; wait covers T+1.k0 planes
        readA(myA, 0, 1);
        if (more) {
            gload_lds16(pB + 32, dB + 8192); gload_lds16(pB + halfA + 32, dB + 24576);
            asm volatile("s_waitcnt vmcnt(4)" ::: "memory");
        }
        BAR();
        mfma16(0);
        BAR();
        pA += 64; pB += 64;
    };

    #pragma unroll 1
    for (int T = 0; T < NT - 2; T += 2) { TILE(0, true); TILE(1, true); }
    TILE(0, true);    // T = NT-2
    TILE(1, false);   // T = NT-1 (drain at P2)

    // LoRA tail: one 32-wide K-step from TW [rows][32] / Bepi [cols][32].
    {
        constexpr int q2 = NT & 1;   // 0 for NT even
        stage_chunk32(TWb + (size_t)row0 * 32,          lds + (q2 << 15) + 0,     t);
        stage_chunk32(TWb + (size_t)(row0 + 128) * 32,  lds + (q2 << 15) + 16384, t);
        stage_chunk32(Bepi + (size_t)col0 * 32,         lds + 65536 + (q2 << 15) + 0,     t);
        stage_chunk32(Bepi + (size_t)(col0 + 128) * 32, lds + 65536 + (q2 << 15) + 16384, t);
        asm volatile("s_waitcnt vmcnt(0)" ::: "memory");
        __builtin_amdgcn_s_barrier();
        char* lA_ = lds + (q2 << 15) + (wm << 14);
        char* lB_ = lds + 65536 + (q2 << 15) + (wnh << 14);
        #pragma unroll
        for (int nf = 0; nf < 4; ++nf)
            bF[nf] = *(const bf16x8*)(lB_ + (((wn & 1) * 64 + nf * 16 + r15) << 6) + swb);
        #pragma unroll
        for (int i = 0; i < 4; ++i)
            aF[i] = *(const bf16x8*)(lA_ + ((i * 16 + r15) << 6) + swb);
        mfma16(0);
        #pragma unroll
        for (int i = 0; i < 4; ++i)
            aF[i] = *(const bf16x8*)(lA_ + (((i + 4) * 16 + r15) << 6) + swb);
        mfma16(4);
    }

    // Epilogue (direct stores, known correct): bias + relu, bf16.
    const int orow = row0 + wm * 128 + (lane >> 4) * 4;
    const int ocol = col0 + wn * 64 + r15;
    #pragma unroll
    for (int nf = 0; nf < 4; ++nf) {
        const int col = ocol + nf * 16;
        const float bn = bias[col];
        #pragma unroll
        for (int mf = 0; mf < 8; ++mf) {
            const int rbase = orow + mf * 16;
            #pragma unroll
            for (int i = 0; i < 4; ++i) {
                const float v = fmaxf(acc[mf][nf][i] + bn, 0.f);
                outp[(size_t)(rbase + i) * N + col] = (__bf16)v;
            }
        }
    }
    #undef BAR
}

// ---------------- old 128x128 GEMM (kept for layer 3: N=512)
#define BM 128
#define BN 128
#define BK 32

template<bool OUT_F32>
__global__ void __launch_bounds__(256) gemm_lora(
    const bf16_t* __restrict__ Abuf, const bf16_t* __restrict__ Wbuf,
    const float* __restrict__ bias, const bf16_t* __restrict__ TWb,
    const bf16_t* __restrict__ Bepi, void* __restrict__ outp,
    const int N, const int K)
{
    __shared__ bf16_t lA[BM * BK];
    __shared__ bf16_t lB[BN * BK];
    const int t = threadIdx.x;
    const int row0 = blockIdx.y * BM;
    const int col0 = blockIdx.x * BN;
    const int wid = t >> 6, lane = t & 63;
    const int wr = wid >> 1, wc = wid & 1;
    const int ln15 = lane & 15, kg = (lane >> 4) * 8;
    const int srow = t >> 2, sg8 = (t & 3) * 8;
    const bf16_t* gA = Abuf + (size_t)(row0 + srow) * K + sg8;
    const bf16_t* gB = Wbuf + (size_t)(col0 + srow) * K + sg8;
    bf16_t* ldA  = &lA[t * 8];
    bf16_t* ldA2 = &lA[2048 + t * 8];
    bf16_t* ldB  = &lB[t * 8];
    bf16_t* ldB2 = &lB[2048 + t * 8];
    f32x4 acc[4][4] = {};
    const int aoff = (wr * 64 + ln15) * BK + kg;
    const int boff = (wc * 64 + ln15) * BK + kg;

    auto compute_tile = [&]() {
        bf16x8 af[4], bfr[4];
        #pragma unroll
        for (int m = 0; m < 4; ++m) af[m] = *(const bf16x8*)&lA[aoff + m * 16 * BK];
        #pragma unroll
        for (int n = 0; n < 4; ++n) bfr[n] = *(const bf16x8*)&lB[boff + n * 16 * BK];
        #pragma unroll
        for (int m = 0; m < 4; ++m)
            #pragma unroll
            for (int n = 0; n < 4; ++n)
                acc[m][n] = __builtin_amdgcn_mfma_f32_16x16x32_bf16(af[m], bfr[n], acc[m][n], 0, 0, 0);
    };

    const size_t half = (size_t)64 * K;
    const int nk = K / BK;
    for (int kt = 0; kt < nk; ++kt) {
        gload_lds16(gA + kt * BK, ldA);
        gload_lds16(gA + half + kt * BK, ldA2);
        gload_lds16(gB + kt * BK, ldB);
        gload_lds16(gB + half + kt * BK, ldB2);
        __syncthreads();
        compute_tile();
        __syncthreads();
    }
    gload_lds16(TWb + (size_t)(row0 + srow) * 32 + sg8, ldA);
    gload_lds16(TWb + (size_t)(row0 + 64 + srow) * 32 + sg8, ldA2);
    gload_lds16(Bepi + (size_t)(col0 + srow) * 32 + sg8, ldB);
    gload_lds16(Bepi + (size_t)(col0 + 64 + srow) * 32 + sg8, ldB2);
    __syncthreads();
    compute_tile();

    const int orow = row0 + wr * 64 + (lane >> 4) * 4;
    const int ocol = col0 + wc * 64 + ln15;
    #pragma unroll
    for (int n = 0; n < 4; ++n) {
        const int col = ocol + n * 16;
        const float bn = bias[col];
        #pragma unroll
        for (int m = 0; m < 4; ++m) {
            const int rbase = orow + m * 16;
            #pragma unroll
            for (int i = 0; i < 4; ++i) {
                const float v = fmaxf(acc[m][n][i] + bn, 0.f);
                if constexpr (OUT_F32)
                    ((float*)outp)[(size_t)(rbase + i) * N + col] = v;
                else
                    ((bf16_t*)outp)[(size_t)(rbase + i) * N + col] = (__bf16)v;
            }
        }
    }
}

extern "C" void kernel_launch(void* const* d_in, const int* in_sizes, int n_in,
                              void* d_out, int out_size, void* d_ws, size_t ws_size,
                              hipStream_t stream)
{
    const float* x    = (const float*)d_in[0];
    const int*   dom  = (const int*)d_in[1];
    const float* W1   = (const float*)d_in[2];  const float* b1  = (const float*)d_in[3];
    const float* W2   = (const float*)d_in[4];  const float* b2  = (const float*)d_in[5];
    const float* W3   = (const float*)d_in[6];  const float* b3  = (const float*)d_in[7];
    const float* A1   = (const float*)d_in[8];  const float* B1  = (const float*)d_in[9];
    const float* A2   = (const float*)d_in[10]; const float* B2  = (const float*)d_in[11];
    const float* A3   = (const float*)d_in[12]; const float* B3  = (const float*)d_in[13];
    const float* dome = (const float*)d_in[14]; const float* lpos = (const float*)d_in[15];
    const float* Wi1  = (const float*)d_in[16]; const float* bi1 = (const float*)d_in[17];
    const float* Wi2  = (const float*)d_in[18]; const float* bi2 = (const float*)d_in[19];
    const float* Wa1  = (const float*)d_in[20]; const float* ba1 = (const float*)d_in[21];
    const float* Wa2  = (const float*)d_in[22]; const float* ba2 = (const float*)d_in[23];
    const float* gate = (const float*)d_in[24]; const float* Rb  = (const float*)d_in[25];
    (void)in_sizes; (void)n_in; (void)out_size; (void)ws_size;

    constexpr int Bsz = 16384, D0 = 2048, D1 = 2048, D2 = 1024, D3 = 512;

    char* ws = (char*)d_ws;
    size_t off = 0;
    auto alloc = [&](size_t bytes) -> void* {
        void* p = ws + off;
        off = (off + bytes + 255) & ~(size_t)255;
        return p;
    };
    float*  salpha = (float*) alloc(8 * 3 * 4 * sizeof(float));
    bf16_t* W1b = (bf16_t*)alloc((size_t)D1 * D0 * 2);
    bf16_t* W2b = (bf16_t*)alloc((size_t)D2 * D1 * 2);
    bf16_t* W3b = (bf16_t*)alloc((size_t)D3 * D2 * 2);
    bf16_t* Ac1 = (bf16_t*)alloc((size_t)32 * D0 * 2);
    bf16_t* Ac2 = (bf16_t*)alloc((size_t)32 * D1 * 2);
    bf16_t* Ac3 = (bf16_t*)alloc((size_t)32 * D2 * 2);
    bf16_t* Be1 = (bf16_t*)alloc((size_t)D1 * 32 * 2);
    bf16_t* Be2 = (bf16_t*)alloc((size_t)D2 * 32 * 2);
    bf16_t* Be3 = (bf16_t*)alloc((size_t)D3 * 32 * 2);
    bf16_t* TWb = (bf16_t*)alloc((size_t)Bsz * 32 * 2);
    bf16_t* xb  = (bf16_t*)alloc((size_t)Bsz * D0 * 2);
    bf16_t* h1b = (bf16_t*)alloc((size_t)Bsz * D1 * 2);
    bf16_t* h2b = xb;  // xb dead after layer-1 GEMM

    routing_kernel<<<1, 256, 0, stream>>>(dome, lpos, Wi1, bi1, Wi2, bi2,
                                          Wa1, ba1, Wa2, ba2, gate, Rb, salpha);

    cvt_fused<<<6816, 256, 0, stream>>>(W1, W2, W3, A1, A2, A3, W1b);
    bepi_fused<<<448, 256, 0, stream>>>(B1, B2, B3, Be1);

    // layer 1: K = D0 = 2048, N = D1 = 2048 (grid 512)
    tw_kernel<true><<<Bsz / 64, 256, 0, stream>>>(x, xb, Ac1, salpha, dom, 0, D0, TWb);
    gemm_lora8<2048><<<(Bsz / 256) * (D1 / 256), 512, 0, stream>>>(xb, W1b, b1, TWb, Be1, h1b, D1, D1 / 256);
    // layer 2: K = D1 = 2048 (NOT D2 — R8/R9 bug), N = D2 = 1024 (grid 256)
    tw_kernel<false><<<Bsz / 64, 256, 0, stream>>>(h1b, nullptr, Ac2, salpha, dom, 1, D1, TWb);
    gemm_lora8<2048><<<(Bsz / 256) * (D2 / 256), 512, 0, stream>>>(h1b, W2b, b2, TWb, Be2, h2b, D2, D2 / 256);
    // layer 3 (f32 out, old 128^2 kernel): K = D2 = 1024
    tw_kernel<false><<<Bsz / 64, 256, 0, stream>>>(h2b, nullptr, Ac3, salpha, dom, 2, D2, TWb);
    gemm_lora<true><<<dim3(D3 / BN, Bsz / BM), 256, 0, stream>>>(h2b, W3b, b3, TWb, Be3, d_out, D3, D2);
}